// Round 1
// baseline (395.808 us; speedup 1.0000x reference)
//
#include <hip/hip_runtime.h>
#include <math.h>

#define B_ 4
#define C_ 512
#define N_ 4096
#define LOG2E 1.44269504088896f

typedef __attribute__((ext_vector_type(8))) short s8v;   // 8 bf16
typedef __attribute__((ext_vector_type(4))) float f4v;   // MFMA acc

#define MF32(a, b, c) __builtin_amdgcn_mfma_f32_16x16x32_bf16(a, b, c, 0, 0, 0)

#if defined(__has_builtin) && __has_builtin(__builtin_amdgcn_exp2f)
#define EXP2(x) __builtin_amdgcn_exp2f(x)
#else
#define EXP2(x) exp2f(x)
#endif

static __device__ __forceinline__ ushort f2bf(float f) {   // RNE
    unsigned u = __float_as_uint(f);
    u += 0x7FFFu + ((u >> 16) & 1u);
    return (ushort)(u >> 16);
}
static __device__ __forceinline__ unsigned pack2bf(float a, float b) {
    unsigned ua = __float_as_uint(a); ua += 0x7FFFu + ((ua >> 16) & 1u);
    unsigned ub = __float_as_uint(b); ub += 0x7FFFu + ((ub >> 16) & 1u);
    return (ua >> 16) | (ub & 0xffff0000u);
}

// ---------------------------------------------------------------------------
// Pass A: Wq|Wk|Wv -> Wb [640][512] bf16
// ---------------------------------------------------------------------------
__global__ __launch_bounds__(256) void wconv_kernel(
    const float* __restrict__ Wq, const float* __restrict__ Wk,
    const float* __restrict__ Wv, ushort* __restrict__ Wb)
{
    const int row = blockIdx.x;
    const float* src = row < 64 ? Wq + (size_t)row * C_
                     : row < 128 ? Wk + (size_t)(row - 64) * C_
                     : Wv + (size_t)(row - 128) * C_;
    const int t2 = threadIdx.x * 2;
    float2 v = *(const float2*)&src[t2];
    ushort2 o; o.x = f2bf(v.x); o.y = f2bf(v.y);
    *(ushort2*)&Wb[(size_t)row * C_ + t2] = o;
}

// ---------------------------------------------------------------------------
// Pass B: fused QKV (x read ONCE, transposed+converted in-LDS, MFMA GEMM).
// grid (N/32 = 128 n-tiles, B), block 512 (8 waves).
// LDS: Xs [32 n][544 c] bf16 (stride 544 shorts: 16B-aligned, bank-uniform).
// Wave w: o-rows w*80..w*80+79 (5 tiles of 16) x 32 n. Rows <64 q (x log2e),
// <128 k (both stored transposed [b][n][64]); rows >=128: v with SWAPPED
// MFMA operands (D[m=n][col=o]) -> ushort4 stores along n into vB [b][c][n].
// ---------------------------------------------------------------------------
__global__ __launch_bounds__(512, 2) void qkv_fused(
    const float* __restrict__ x, const ushort* __restrict__ Wb,
    const float* __restrict__ bq, const float* __restrict__ bk,
    const float* __restrict__ bv,
    ushort* __restrict__ qT, ushort* __restrict__ kT, ushort* __restrict__ vB)
{
    __shared__ ushort Xs[32 * 544];

    const int tid = threadIdx.x, w = tid >> 6, lane = tid & 63;
    const int li = lane & 15, qd = lane >> 4;
    const int n0 = blockIdx.x * 32, b = blockIdx.y;

    // ---- stage x[c][n0..n0+31] -> Xs[n][c] bf16 ----
    {
        const int cg = tid >> 3;       // 0..63
        const int ch = tid & 7;        // n-chunk of 4
        #pragma unroll
        for (int r = 0; r < 8; ++r) {
            const int c = r * 64 + cg;
            float4 v = *(const float4*)&x[((size_t)b * C_ + c) * N_ + n0 + ch * 4];
            Xs[(ch * 4 + 0) * 544 + c] = f2bf(v.x);
            Xs[(ch * 4 + 1) * 544 + c] = f2bf(v.y);
            Xs[(ch * 4 + 2) * 544 + c] = f2bf(v.z);
            Xs[(ch * 4 + 3) * 544 + c] = f2bf(v.w);
        }
    }
    __syncthreads();

    const int rb0 = w * 80;
    f4v acc[5][2];
    #pragma unroll
    for (int ot = 0; ot < 5; ++ot)
        #pragma unroll
        for (int nt = 0; nt < 2; ++nt)
            acc[ot][nt] = (f4v){0.f, 0.f, 0.f, 0.f};

    #pragma unroll 2
    for (int kc = 0; kc < C_; kc += 32) {
        s8v aw[5], bx[2];
        #pragma unroll
        for (int ot = 0; ot < 5; ++ot)
            aw[ot] = *(const s8v*)&Wb[(size_t)(rb0 + ot * 16 + li) * C_ + kc + qd * 8];
        #pragma unroll
        for (int nt = 0; nt < 2; ++nt)
            bx[nt] = *(const s8v*)&Xs[(nt * 16 + li) * 544 + kc + qd * 8];
        #pragma unroll
        for (int ot = 0; ot < 5; ++ot) {
            if (rb0 + ot * 16 >= 128) {       // v: swapped -> D[m=n][col=o]
                #pragma unroll
                for (int nt = 0; nt < 2; ++nt)
                    acc[ot][nt] = MF32(bx[nt], aw[ot], acc[ot][nt]);
            } else {                           // q/k: D[m=o][col=n]
                #pragma unroll
                for (int nt = 0; nt < 2; ++nt)
                    acc[ot][nt] = MF32(aw[ot], bx[nt], acc[ot][nt]);
            }
        }
    }

    #pragma unroll
    for (int ot = 0; ot < 5; ++ot) {
        const int rb = rb0 + ot * 16;
        if (rb < 128) {   // q or k: lane col = n, rows = o (qd*4+r)
            ushort* dst = rb < 64 ? qT : kT;
            const float* bias = rb < 64 ? bq : bk;
            const int ob = (rb < 64 ? rb : rb - 64) + qd * 4;
            const float sc = rb < 64 ? LOG2E : 1.0f;
            #pragma unroll
            for (int nt = 0; nt < 2; ++nt) {
                const int n = n0 + nt * 16 + li;
                ushort4 o;
                o.x = f2bf((acc[ot][nt][0] + bias[ob + 0]) * sc);
                o.y = f2bf((acc[ot][nt][1] + bias[ob + 1]) * sc);
                o.z = f2bf((acc[ot][nt][2] + bias[ob + 2]) * sc);
                o.w = f2bf((acc[ot][nt][3] + bias[ob + 3]) * sc);
                *(ushort4*)&dst[((size_t)b * N_ + n) * 64 + ob] = o;
            }
        } else {          // v: lane col = o (c), rows = n
            const int c = rb - 128 + li;
            const float bb = bv[c];
            #pragma unroll
            for (int nt = 0; nt < 2; ++nt) {
                const int n = n0 + nt * 16 + qd * 4;
                ushort4 o;
                o.x = f2bf(acc[ot][nt][0] + bb);
                o.y = f2bf(acc[ot][nt][1] + bb);
                o.z = f2bf(acc[ot][nt][2] + bb);
                o.w = f2bf(acc[ot][nt][3] + bb);
                *(ushort4*)&vB[((size_t)b * C_ + c) * N_ + n] = o;
            }
        }
    }
}

// ---------------------------------------------------------------------------
// Pass C: MFMA flash attention, full-C block (no S redundancy).
// grid (128 i-tiles of 32, B) = 512 blocks (2/CU -> 16 waves/CU for latency
// hiding; was 64 i-tiles = 1 block/CU at 22% occupancy), block 512 (8 waves).
// Wave w: S^T j-slice w*16 (D[m=j][n=i], lane owns i-row li) AND PV c-slice
// w*64. j-tile 128/iter; P ping-pong [32i][136j] bf16 in LDS (1 barrier/iter).
// All global loads are issued early in the barrier interval that consumes
// them (vmcnt(0) drain at the barrier then costs ~0).
// LDS 18432 B. exp2 (log2e folded into q), per-lane l partials.
// ---------------------------------------------------------------------------
__device__ __forceinline__ void pv_chunk(
    const ushort* __restrict__ Pr, int li, int qd, int cidx,
    const s8v* vf, f4v (&acc)[4][2])
{
    s8v pf[2];
    #pragma unroll
    for (int it = 0; it < 2; ++it)
        pf[it] = *(const s8v*)&Pr[(size_t)(it * 16 + li) * 136 + cidx * 32 + qd * 8];
    #pragma unroll
    for (int ct = 0; ct < 4; ++ct)
        #pragma unroll
        for (int it = 0; it < 2; ++it)
            acc[ct][it] = MF32(vf[ct], pf[it], acc[ct][it]);
}

__global__ __launch_bounds__(512, 4) void attn_mfma(
    const ushort* __restrict__ qT, const ushort* __restrict__ kT,
    const ushort* __restrict__ vB, const float* __restrict__ x,
    const float* __restrict__ gamma, float* __restrict__ out)
{
    extern __shared__ char smem[];
    ushort* Pb0 = (ushort*)smem;               // [32][136]
    ushort* Pb1 = (ushort*)(smem + 8704);      // [32][136]
    float*  l_s = (float*)(smem + 17408);      // [8][32]

    const int tid = threadIdx.x, w = tid >> 6, lane = tid & 63;
    const int li = lane & 15, qd = lane >> 4;
    const int i_base = blockIdx.x * 32, b = blockIdx.y;

    const ushort* qTb = qT + (size_t)b * N_ * 64;
    const ushort* kTb = kT + (size_t)b * N_ * 64;
    const ushort* vBb = vB + (size_t)b * C_ * N_;

    // persistent Q fragments (B-operand: n=i at li, k=c at qd*8)
    s8v qf[2][2];
    #pragma unroll
    for (int it = 0; it < 2; ++it)
        #pragma unroll
        for (int ks = 0; ks < 2; ++ks)
            qf[it][ks] = *(const s8v*)&qTb[(size_t)(i_base + it * 16 + li) * 64 + ks * 32 + qd * 8];

    f4v acc[4][2];   // [ct][it]: c = w*64+ct*16+qd*4+r, i = i_base+it*16+li
    #pragma unroll
    for (int ct = 0; ct < 4; ++ct)
        #pragma unroll
        for (int it = 0; it < 2; ++it)
            acc[ct][it] = (f4v){0.f, 0.f, 0.f, 0.f};
    float lp[2] = {0.f, 0.f};

    const ushort* kptr = kTb + (size_t)(w * 16 + li) * 64 + qd * 8;
    const ushort* vptr[4];
    #pragma unroll
    for (int ct = 0; ct < 4; ++ct)
        vptr[ct] = vBb + (size_t)(w * 64 + ct * 16 + li) * N_ + qd * 8;

    // ---- prologue (interval 0): K(0), V(0)ch0/1, S(0), P(0)->Pb0 ----
    s8v kf0 = *(const s8v*)(kptr);
    s8v kf1 = *(const s8v*)(kptr + 32);
    s8v vcur[8];
    #pragma unroll
    for (int c = 0; c < 2; ++c)
        #pragma unroll
        for (int ct = 0; ct < 4; ++ct)
            vcur[c * 4 + ct] = *(const s8v*)(vptr[ct] + c * 32);

    f4v sac[2];
    #pragma unroll
    for (int it = 0; it < 2; ++it) {
        sac[it] = (f4v){0.f, 0.f, 0.f, 0.f};
        sac[it] = MF32(kf0, qf[it][0], sac[it]);
        sac[it] = MF32(kf1, qf[it][1], sac[it]);
    }
    #pragma unroll
    for (int it = 0; it < 2; ++it) {
        const float p0 = EXP2(sac[it][0]);
        const float p1 = EXP2(sac[it][1]);
        const float p2 = EXP2(sac[it][2]);
        const float p3 = EXP2(sac[it][3]);
        lp[it] += (p0 + p1) + (p2 + p3);
        uint2 u; u.x = pack2bf(p0, p1); u.y = pack2bf(p2, p3);
        *(uint2*)&Pb0[(size_t)(it * 16 + li) * 136 + w * 16 + qd * 4] = u;
    }
    __syncthreads();

    // ---- steady: interval t does PV(t-1) + S(t); one barrier ----
    #pragma unroll 1
    for (int t = 1; t < N_ / 128; ++t) {
        const ushort* Pr = ((t - 1) & 1) ? Pb1 : Pb0;
        ushort*       Pw = ((t - 1) & 1) ? Pb0 : Pb1;
        const size_t jprev = (size_t)(t - 1) * 128;
        const size_t jcur  = (size_t)t * 128;

        // top: K(t) (consumed at S(t), ~1024 cyc away)
        s8v nk0 = *(const s8v*)(kptr + jcur * 64);
        s8v nk1 = *(const s8v*)(kptr + jcur * 64 + 32);

        // PV(t-1) with rolling V prefetch (each load covered by >=1 chunk of MFMA)
        s8v vlt0[4], vlt1[4], vnx[8];
        #pragma unroll
        for (int ct = 0; ct < 4; ++ct)                       // V(t-1) ch2
            vlt0[ct] = *(const s8v*)(vptr[ct] + jprev + 2 * 32);
        pv_chunk(Pr, li, qd, 0, &vcur[0], acc);
        #pragma unroll
        for (int ct = 0; ct < 4; ++ct)                       // V(t-1) ch3
            vlt1[ct] = *(const s8v*)(vptr[ct] + jprev + 3 * 32);
        pv_chunk(Pr, li, qd, 1, &vcur[4], acc);
        #pragma unroll
        for (int ct = 0; ct < 4; ++ct)                       // V(t) ch0 (next interval)
            vnx[ct] = *(const s8v*)(vptr[ct] + jcur);
        pv_chunk(Pr, li, qd, 2, vlt0, acc);
        #pragma unroll
        for (int ct = 0; ct < 4; ++ct)                       // V(t) ch1 (next interval)
            vnx[4 + ct] = *(const s8v*)(vptr[ct] + jcur + 32);
        pv_chunk(Pr, li, qd, 3, vlt1, acc);

        // S(t)
        #pragma unroll
        for (int it = 0; it < 2; ++it) {
            sac[it] = (f4v){0.f, 0.f, 0.f, 0.f};
            sac[it] = MF32(nk0, qf[it][0], sac[it]);
            sac[it] = MF32(nk1, qf[it][1], sac[it]);
        }
        #pragma unroll
        for (int it = 0; it < 2; ++it) {
            const float p0 = EXP2(sac[it][0]);
            const float p1 = EXP2(sac[it][1]);
            const float p2 = EXP2(sac[it][2]);
            const float p3 = EXP2(sac[it][3]);
            lp[it] += (p0 + p1) + (p2 + p3);
            uint2 u; u.x = pack2bf(p0, p1); u.y = pack2bf(p2, p3);
            *(uint2*)&Pw[(size_t)(it * 16 + li) * 136 + w * 16 + qd * 4] = u;
        }
        #pragma unroll
        for (int k = 0; k < 8; ++k) vcur[k] = vnx[k];
        __syncthreads();
    }

    // ---- final PV(T-1) ----
    {
        const ushort* Pr = ((N_ / 128 - 1) & 1) ? Pb1 : Pb0;
        const size_t jprev = (size_t)(N_ / 128 - 1) * 128;
        s8v vlt0[4], vlt1[4];
        #pragma unroll
        for (int ct = 0; ct < 4; ++ct)
            vlt0[ct] = *(const s8v*)(vptr[ct] + jprev + 2 * 32);
        pv_chunk(Pr, li, qd, 0, &vcur[0], acc);
        #pragma unroll
        for (int ct = 0; ct < 4; ++ct)
            vlt1[ct] = *(const s8v*)(vptr[ct] + jprev + 3 * 32);
        pv_chunk(Pr, li, qd, 1, &vcur[4], acc);
        pv_chunk(Pr, li, qd, 2, vlt0, acc);
        pv_chunk(Pr, li, qd, 3, vlt1, acc);
    }

    // ---- l reduction: qd via shfl, waves (j-slices) via LDS ----
    #pragma unroll
    for (int it = 0; it < 2; ++it) {
        lp[it] += __shfl_xor(lp[it], 16, 64);
        lp[it] += __shfl_xor(lp[it], 32, 64);
    }
    if (qd == 0) {
        #pragma unroll
        for (int it = 0; it < 2; ++it) l_s[w * 32 + it * 16 + li] = lp[it];
    }
    __syncthreads();
    float inv[2];
    #pragma unroll
    for (int it = 0; it < 2; ++it) {
        float t = 0.f;
        #pragma unroll
        for (int ww = 0; ww < 8; ++ww) t += l_s[ww * 32 + it * 16 + li];
        inv[it] = 1.0f / t;
    }

    // ---- epilogue: out = gamma * acc / l + x (each (c,i) owned by one wave) ----
    const float g = gamma[0];
    #pragma unroll
    for (int ct = 0; ct < 4; ++ct)
        #pragma unroll
        for (int it = 0; it < 2; ++it) {
            const int i = i_base + it * 16 + li;
            #pragma unroll
            for (int r = 0; r < 4; ++r) {
                const int c = w * 64 + ct * 16 + qd * 4 + r;
                const size_t off = ((size_t)b * C_ + c) * N_ + i;
                out[off] = g * acc[ct][it][r] * inv[it] + x[off];
            }
        }
}

// ---------------------------------------------------------------------------
extern "C" void kernel_launch(void* const* d_in, const int* in_sizes, int n_in,
                              void* d_out, int out_size, void* d_ws, size_t ws_size,
                              hipStream_t stream)
{
    const float* x     = (const float*)d_in[0];
    const float* Wq    = (const float*)d_in[1];
    const float* bq    = (const float*)d_in[2];
    const float* Wk    = (const float*)d_in[3];
    const float* bk    = (const float*)d_in[4];
    const float* Wv    = (const float*)d_in[5];
    const float* bv    = (const float*)d_in[6];
    const float* gamma = (const float*)d_in[7];
    float* out = (float*)d_out;

    // ws (ushort): vB [B][512][N] | qT [B][N][64] | kT [B][N][64] | Wb [640][512]
    ushort* vB = (ushort*)d_ws;
    ushort* qT = vB + (size_t)B_ * C_ * N_;
    ushort* kT = qT + (size_t)B_ * N_ * 64;
    ushort* Wb = kT + (size_t)B_ * N_ * 64;

    wconv_kernel<<<dim3(640), 256, 0, stream>>>(Wq, Wk, Wv, Wb);
    qkv_fused<<<dim3(N_ / 32, B_), 512, 0, stream>>>(x, Wb, bq, bk, bv, qT, kT, vB);
    attn_mfma<<<dim3(N_ / 32, B_), 512, 18432, stream>>>(qT, kT, vB, x, gamma, out);
}

// Round 2
// 270.428 us; speedup vs baseline: 1.4636x; 1.4636x over previous
//
#include <hip/hip_runtime.h>
#include <math.h>

#define B_ 4
#define C_ 512
#define N_ 4096
#define LOG2E 1.44269504088896f

typedef __attribute__((ext_vector_type(8))) short s8v;   // 8 bf16
typedef __attribute__((ext_vector_type(4))) float f4v;   // MFMA acc

#define MF32(a, b, c) __builtin_amdgcn_mfma_f32_16x16x32_bf16(a, b, c, 0, 0, 0)

#if defined(__has_builtin) && __has_builtin(__builtin_amdgcn_exp2f)
#define EXP2(x) __builtin_amdgcn_exp2f(x)
#else
#define EXP2(x) exp2f(x)
#endif

// Raw barrier: drains LDS ops only (cross-wave P visibility); global-load
// prefetches stay IN FLIGHT across the barrier (HK/T4 pattern). Compiler
// inserts counted vmcnt(N) at actual consumption points.
#define BARRIER_LDS() do {                                   \
    __builtin_amdgcn_sched_barrier(0);                       \
    asm volatile("s_waitcnt lgkmcnt(0)" ::: "memory");       \
    __builtin_amdgcn_s_barrier();                            \
    __builtin_amdgcn_sched_barrier(0);                       \
} while (0)

static __device__ __forceinline__ ushort f2bf(float f) {   // RNE
    unsigned u = __float_as_uint(f);
    u += 0x7FFFu + ((u >> 16) & 1u);
    return (ushort)(u >> 16);
}
static __device__ __forceinline__ unsigned pack2bf(float a, float b) {
    unsigned ua = __float_as_uint(a); ua += 0x7FFFu + ((ua >> 16) & 1u);
    unsigned ub = __float_as_uint(b); ub += 0x7FFFu + ((ub >> 16) & 1u);
    return (ua >> 16) | (ub & 0xffff0000u);
}

// ---------------------------------------------------------------------------
// Pass A: Wq|Wk|Wv -> Wb [640][512] bf16
// ---------------------------------------------------------------------------
__global__ __launch_bounds__(256) void wconv_kernel(
    const float* __restrict__ Wq, const float* __restrict__ Wk,
    const float* __restrict__ Wv, ushort* __restrict__ Wb)
{
    const int row = blockIdx.x;
    const float* src = row < 64 ? Wq + (size_t)row * C_
                     : row < 128 ? Wk + (size_t)(row - 64) * C_
                     : Wv + (size_t)(row - 128) * C_;
    const int t2 = threadIdx.x * 2;
    float2 v = *(const float2*)&src[t2];
    ushort2 o; o.x = f2bf(v.x); o.y = f2bf(v.y);
    *(ushort2*)&Wb[(size_t)row * C_ + t2] = o;
}

// ---------------------------------------------------------------------------
// Pass B: fused QKV (x read ONCE, transposed+converted in-LDS, MFMA GEMM).
// grid (N/32 = 128 n-tiles, B), block 512 (8 waves).
// ---------------------------------------------------------------------------
__global__ __launch_bounds__(512, 2) void qkv_fused(
    const float* __restrict__ x, const ushort* __restrict__ Wb,
    const float* __restrict__ bq, const float* __restrict__ bk,
    const float* __restrict__ bv,
    ushort* __restrict__ qT, ushort* __restrict__ kT, ushort* __restrict__ vB)
{
    __shared__ ushort Xs[32 * 544];

    const int tid = threadIdx.x, w = tid >> 6, lane = tid & 63;
    const int li = lane & 15, qd = lane >> 4;
    const int n0 = blockIdx.x * 32, b = blockIdx.y;

    // ---- stage x[c][n0..n0+31] -> Xs[n][c] bf16 ----
    {
        const int cg = tid >> 3;       // 0..63
        const int ch = tid & 7;        // n-chunk of 4
        #pragma unroll
        for (int r = 0; r < 8; ++r) {
            const int c = r * 64 + cg;
            float4 v = *(const float4*)&x[((size_t)b * C_ + c) * N_ + n0 + ch * 4];
            Xs[(ch * 4 + 0) * 544 + c] = f2bf(v.x);
            Xs[(ch * 4 + 1) * 544 + c] = f2bf(v.y);
            Xs[(ch * 4 + 2) * 544 + c] = f2bf(v.z);
            Xs[(ch * 4 + 3) * 544 + c] = f2bf(v.w);
        }
    }
    __syncthreads();

    const int rb0 = w * 80;
    f4v acc[5][2];
    #pragma unroll
    for (int ot = 0; ot < 5; ++ot)
        #pragma unroll
        for (int nt = 0; nt < 2; ++nt)
            acc[ot][nt] = (f4v){0.f, 0.f, 0.f, 0.f};

    #pragma unroll 2
    for (int kc = 0; kc < C_; kc += 32) {
        s8v aw[5], bx[2];
        #pragma unroll
        for (int ot = 0; ot < 5; ++ot)
            aw[ot] = *(const s8v*)&Wb[(size_t)(rb0 + ot * 16 + li) * C_ + kc + qd * 8];
        #pragma unroll
        for (int nt = 0; nt < 2; ++nt)
            bx[nt] = *(const s8v*)&Xs[(nt * 16 + li) * 544 + kc + qd * 8];
        #pragma unroll
        for (int ot = 0; ot < 5; ++ot) {
            if (rb0 + ot * 16 >= 128) {       // v: swapped -> D[m=n][col=o]
                #pragma unroll
                for (int nt = 0; nt < 2; ++nt)
                    acc[ot][nt] = MF32(bx[nt], aw[ot], acc[ot][nt]);
            } else {                           // q/k: D[m=o][col=n]
                #pragma unroll
                for (int nt = 0; nt < 2; ++nt)
                    acc[ot][nt] = MF32(aw[ot], bx[nt], acc[ot][nt]);
            }
        }
    }

    #pragma unroll
    for (int ot = 0; ot < 5; ++ot) {
        const int rb = rb0 + ot * 16;
        if (rb < 128) {   // q or k: lane col = n, rows = o (qd*4+r)
            ushort* dst = rb < 64 ? qT : kT;
            const float* bias = rb < 64 ? bq : bk;
            const int ob = (rb < 64 ? rb : rb - 64) + qd * 4;
            const float sc = rb < 64 ? LOG2E : 1.0f;
            #pragma unroll
            for (int nt = 0; nt < 2; ++nt) {
                const int n = n0 + nt * 16 + li;
                ushort4 o;
                o.x = f2bf((acc[ot][nt][0] + bias[ob + 0]) * sc);
                o.y = f2bf((acc[ot][nt][1] + bias[ob + 1]) * sc);
                o.z = f2bf((acc[ot][nt][2] + bias[ob + 2]) * sc);
                o.w = f2bf((acc[ot][nt][3] + bias[ob + 3]) * sc);
                *(ushort4*)&dst[((size_t)b * N_ + n) * 64 + ob] = o;
            }
        } else {          // v: lane col = o (c), rows = n
            const int c = rb - 128 + li;
            const float bb = bv[c];
            #pragma unroll
            for (int nt = 0; nt < 2; ++nt) {
                const int n = n0 + nt * 16 + qd * 4;
                ushort4 o;
                o.x = f2bf(acc[ot][nt][0] + bb);
                o.y = f2bf(acc[ot][nt][1] + bb);
                o.z = f2bf(acc[ot][nt][2] + bb);
                o.w = f2bf(acc[ot][nt][3] + bb);
                *(ushort4*)&vB[((size_t)b * C_ + c) * N_ + n] = o;
            }
        }
    }
}

// ---------------------------------------------------------------------------
// Pass C: MFMA flash attention, full-C block (no S redundancy).
// grid (64 i-tiles of 64, B) = 256 blocks (1/CU), block 512 (8 waves).
// Wave w: S^T j-slice w*16 (D[m=j][n=i], lane owns i-row li) AND PV c-slice
// w*64. j-tile 128/iter; P ping-pong [64i][136j] bf16 in LDS.
// KEY CHANGE vs 152us baseline: in-loop barrier is raw s_barrier +
// lgkmcnt(0)-only (LDS visibility for P); V/K global prefetches stay in
// flight ACROSS the barrier (no vmcnt(0) drain per iteration). K is
// prefetched one full iteration ahead (~3000 cyc coverage).
// LDS 36864 B. exp2 (log2e folded into q), per-lane l partials.
// ---------------------------------------------------------------------------
__device__ __forceinline__ void pv_chunk(
    const ushort* __restrict__ Pr, int li, int qd, int cidx,
    const s8v* vf, f4v (&acc)[4][4])
{
    s8v pf[4];
    #pragma unroll
    for (int it = 0; it < 4; ++it)
        pf[it] = *(const s8v*)&Pr[(size_t)(it * 16 + li) * 136 + cidx * 32 + qd * 8];
    #pragma unroll
    for (int ct = 0; ct < 4; ++ct)
        #pragma unroll
        for (int it = 0; it < 4; ++it)
            acc[ct][it] = MF32(vf[ct], pf[it], acc[ct][it]);
}

__global__ __launch_bounds__(512, 2) void attn_mfma(
    const ushort* __restrict__ qT, const ushort* __restrict__ kT,
    const ushort* __restrict__ vB, const float* __restrict__ x,
    const float* __restrict__ gamma, float* __restrict__ out)
{
    extern __shared__ char smem[];
    ushort* Pb0 = (ushort*)smem;               // [64][136]
    ushort* Pb1 = (ushort*)(smem + 17408);     // [64][136]
    float*  l_s = (float*)(smem + 34816);      // [8][64]

    const int tid = threadIdx.x, w = tid >> 6, lane = tid & 63;
    const int li = lane & 15, qd = lane >> 4;
    const int i_base = blockIdx.x * 64, b = blockIdx.y;

    const ushort* qTb = qT + (size_t)b * N_ * 64;
    const ushort* kTb = kT + (size_t)b * N_ * 64;
    const ushort* vBb = vB + (size_t)b * C_ * N_;

    // persistent Q fragments (B-operand: n=i at li, k=c at qd*8)
    s8v qf[4][2];
    #pragma unroll
    for (int it = 0; it < 4; ++it)
        #pragma unroll
        for (int ks = 0; ks < 2; ++ks)
            qf[it][ks] = *(const s8v*)&qTb[(size_t)(i_base + it * 16 + li) * 64 + ks * 32 + qd * 8];

    f4v acc[4][4];   // [ct][it]: c = w*64+ct*16+qd*4+r, i = i_base+it*16+li
    #pragma unroll
    for (int ct = 0; ct < 4; ++ct)
        #pragma unroll
        for (int it = 0; it < 4; ++it)
            acc[ct][it] = (f4v){0.f, 0.f, 0.f, 0.f};
    float lp[4] = {0.f, 0.f, 0.f, 0.f};

    const ushort* kptr = kTb + (size_t)(w * 16 + li) * 64 + qd * 8;
    const ushort* vptr[4];
    #pragma unroll
    for (int ct = 0; ct < 4; ++ct)
        vptr[ct] = vBb + (size_t)(w * 64 + ct * 16 + li) * N_ + qd * 8;

    // ---- prologue (interval 0): K(0), V(0)ch0/1, S(0), P(0)->Pb0, K(1) ----
    s8v kc0 = *(const s8v*)(kptr);
    s8v kc1 = *(const s8v*)(kptr + 32);
    s8v vcur[8];
    #pragma unroll
    for (int c = 0; c < 2; ++c)
        #pragma unroll
        for (int ct = 0; ct < 4; ++ct)
            vcur[c * 4 + ct] = *(const s8v*)(vptr[ct] + c * 32);

    f4v sac[4];
    #pragma unroll
    for (int it = 0; it < 4; ++it) {
        sac[it] = (f4v){0.f, 0.f, 0.f, 0.f};
        sac[it] = MF32(kc0, qf[it][0], sac[it]);
        sac[it] = MF32(kc1, qf[it][1], sac[it]);
    }
    // K(1) prefetch: issued now, consumed at S(1) next interval (stays in
    // flight across the raw barrier).
    s8v kn0 = *(const s8v*)(kptr + (size_t)128 * 64);
    s8v kn1 = *(const s8v*)(kptr + (size_t)128 * 64 + 32);

    #pragma unroll
    for (int it = 0; it < 4; ++it) {
        const float p0 = EXP2(sac[it][0]);
        const float p1 = EXP2(sac[it][1]);
        const float p2 = EXP2(sac[it][2]);
        const float p3 = EXP2(sac[it][3]);
        lp[it] += (p0 + p1) + (p2 + p3);
        uint2 u; u.x = pack2bf(p0, p1); u.y = pack2bf(p2, p3);
        *(uint2*)&Pb0[(size_t)(it * 16 + li) * 136 + w * 16 + qd * 4] = u;
    }
    BARRIER_LDS();

    // ---- steady: interval t does PV(t-1) + S(t); one raw barrier ----
    #pragma unroll 1
    for (int t = 1; t < N_ / 128; ++t) {
        const ushort* Pr = ((t - 1) & 1) ? Pb1 : Pb0;
        ushort*       Pw = ((t - 1) & 1) ? Pb0 : Pb1;
        const size_t jprev = (size_t)(t - 1) * 128;
        const size_t jcur  = (size_t)t * 128;
        // K(t+1) prefetch target (wraps harmlessly to 0 on last iter)
        const size_t jnext = (t + 1 < N_ / 128) ? jcur + 128 : 0;

        // K(t) arrives from last interval's prefetch
        s8v ck0 = kn0, ck1 = kn1;
        kn0 = *(const s8v*)(kptr + jnext * 64);
        kn1 = *(const s8v*)(kptr + jnext * 64 + 32);

        // PV(t-1) with rolling V prefetch (each load covered by >=1 chunk of MFMA)
        s8v vlt0[4], vlt1[4], vnx[8];
        #pragma unroll
        for (int ct = 0; ct < 4; ++ct)                       // V(t-1) ch2
            vlt0[ct] = *(const s8v*)(vptr[ct] + jprev + 2 * 32);
        pv_chunk(Pr, li, qd, 0, &vcur[0], acc);
        #pragma unroll
        for (int ct = 0; ct < 4; ++ct)                       // V(t-1) ch3
            vlt1[ct] = *(const s8v*)(vptr[ct] + jprev + 3 * 32);
        pv_chunk(Pr, li, qd, 1, &vcur[4], acc);
        #pragma unroll
        for (int ct = 0; ct < 4; ++ct)                       // V(t) ch0 (next interval)
            vnx[ct] = *(const s8v*)(vptr[ct] + jcur);
        pv_chunk(Pr, li, qd, 2, vlt0, acc);
        #pragma unroll
        for (int ct = 0; ct < 4; ++ct)                       // V(t) ch1 (next interval)
            vnx[4 + ct] = *(const s8v*)(vptr[ct] + jcur + 32);
        pv_chunk(Pr, li, qd, 3, vlt1, acc);

        // S(t)
        #pragma unroll
        for (int it = 0; it < 4; ++it) {
            sac[it] = (f4v){0.f, 0.f, 0.f, 0.f};
            sac[it] = MF32(ck0, qf[it][0], sac[it]);
            sac[it] = MF32(ck1, qf[it][1], sac[it]);
        }
        #pragma unroll
        for (int it = 0; it < 4; ++it) {
            const float p0 = EXP2(sac[it][0]);
            const float p1 = EXP2(sac[it][1]);
            const float p2 = EXP2(sac[it][2]);
            const float p3 = EXP2(sac[it][3]);
            lp[it] += (p0 + p1) + (p2 + p3);
            uint2 u; u.x = pack2bf(p0, p1); u.y = pack2bf(p2, p3);
            *(uint2*)&Pw[(size_t)(it * 16 + li) * 136 + w * 16 + qd * 4] = u;
        }
        #pragma unroll
        for (int k = 0; k < 8; ++k) vcur[k] = vnx[k];
        BARRIER_LDS();
    }

    // ---- final PV(T-1) ----
    {
        const ushort* Pr = ((N_ / 128 - 1) & 1) ? Pb1 : Pb0;
        const size_t jprev = (size_t)(N_ / 128 - 1) * 128;
        s8v vlt0[4], vlt1[4];
        #pragma unroll
        for (int ct = 0; ct < 4; ++ct)
            vlt0[ct] = *(const s8v*)(vptr[ct] + jprev + 2 * 32);
        pv_chunk(Pr, li, qd, 0, &vcur[0], acc);
        #pragma unroll
        for (int ct = 0; ct < 4; ++ct)
            vlt1[ct] = *(const s8v*)(vptr[ct] + jprev + 3 * 32);
        pv_chunk(Pr, li, qd, 1, &vcur[4], acc);
        pv_chunk(Pr, li, qd, 2, vlt0, acc);
        pv_chunk(Pr, li, qd, 3, vlt1, acc);
    }

    // ---- l reduction: qd via shfl, waves (j-slices) via LDS ----
    #pragma unroll
    for (int it = 0; it < 4; ++it) {
        lp[it] += __shfl_xor(lp[it], 16, 64);
        lp[it] += __shfl_xor(lp[it], 32, 64);
    }
    if (qd == 0) {
        #pragma unroll
        for (int it = 0; it < 4; ++it) l_s[w * 64 + it * 16 + li] = lp[it];
    }
    __syncthreads();
    float inv[4];
    #pragma unroll
    for (int it = 0; it < 4; ++it) {
        float t = 0.f;
        #pragma unroll
        for (int ww = 0; ww < 8; ++ww) t += l_s[ww * 64 + it * 16 + li];
        inv[it] = 1.0f / t;
    }

    // ---- epilogue: out = gamma * acc / l + x (each (c,i) owned by one wave) ----
    const float g = gamma[0];
    #pragma unroll
    for (int ct = 0; ct < 4; ++ct)
        #pragma unroll
        for (int it = 0; it < 4; ++it) {
            const int i = i_base + it * 16 + li;
            #pragma unroll
            for (int r = 0; r < 4; ++r) {
                const int c = w * 64 + ct * 16 + qd * 4 + r;
                const size_t off = ((size_t)b * C_ + c) * N_ + i;
                out[off] = g * acc[ct][it][r] * inv[it] + x[off];
            }
        }
}

// ---------------------------------------------------------------------------
extern "C" void kernel_launch(void* const* d_in, const int* in_sizes, int n_in,
                              void* d_out, int out_size, void* d_ws, size_t ws_size,
                              hipStream_t stream)
{
    const float* x     = (const float*)d_in[0];
    const float* Wq    = (const float*)d_in[1];
    const float* bq    = (const float*)d_in[2];
    const float* Wk    = (const float*)d_in[3];
    const float* bk    = (const float*)d_in[4];
    const float* Wv    = (const float*)d_in[5];
    const float* bv    = (const float*)d_in[6];
    const float* gamma = (const float*)d_in[7];
    float* out = (float*)d_out;

    // ws (ushort): vB [B][512][N] | qT [B][N][64] | kT [B][N][64] | Wb [640][512]
    ushort* vB = (ushort*)d_ws;
    ushort* qT = vB + (size_t)B_ * C_ * N_;
    ushort* kT = qT + (size_t)B_ * N_ * 64;
    ushort* Wb = kT + (size_t)B_ * N_ * 64;

    wconv_kernel<<<dim3(640), 256, 0, stream>>>(Wq, Wk, Wv, Wb);
    qkv_fused<<<dim3(N_ / 32, B_), 512, 0, stream>>>(x, Wb, bq, bk, bv, qT, kT, vB);
    attn_mfma<<<dim3(N_ / 64, B_), 512, 36864, stream>>>(qT, kT, vB, x, gamma, out);
}

// Round 3
// 234.920 us; speedup vs baseline: 1.6849x; 1.1511x over previous
//
#include <hip/hip_runtime.h>
#include <math.h>

#define B_ 4
#define C_ 512
#define N_ 4096
#define LOG2E 1.44269504088896f

typedef __attribute__((ext_vector_type(8))) short s8v;   // 8 bf16
typedef __attribute__((ext_vector_type(4))) float f4v;   // MFMA acc

#define MF32(a, b, c) __builtin_amdgcn_mfma_f32_16x16x32_bf16(a, b, c, 0, 0, 0)

#if defined(__has_builtin) && __has_builtin(__builtin_amdgcn_exp2f)
#define EXP2(x) __builtin_amdgcn_exp2f(x)
#else
#define EXP2(x) exp2f(x)
#endif

// Raw barrier: drains LDS ops only (cross-wave P visibility); global-load
// prefetches stay IN FLIGHT across the barrier. Neutral vs __syncthreads in
// R2 measurement, kept because it is semantically sufficient and never worse.
#define BARRIER_LDS() do {                                   \
    __builtin_amdgcn_sched_barrier(0);                       \
    asm volatile("s_waitcnt lgkmcnt(0)" ::: "memory");       \
    __builtin_amdgcn_s_barrier();                            \
    __builtin_amdgcn_sched_barrier(0);                       \
} while (0)

static __device__ __forceinline__ ushort f2bf(float f) {   // RNE
    unsigned u = __float_as_uint(f);
    u += 0x7FFFu + ((u >> 16) & 1u);
    return (ushort)(u >> 16);
}
static __device__ __forceinline__ unsigned pack2bf(float a, float b) {
    unsigned ua = __float_as_uint(a); ua += 0x7FFFu + ((ua >> 16) & 1u);
    unsigned ub = __float_as_uint(b); ub += 0x7FFFu + ((ub >> 16) & 1u);
    return (ua >> 16) | (ub & 0xffff0000u);
}

// ---------------------------------------------------------------------------
// Pass A: Wq|Wk|Wv -> Wb [640][512] bf16
// ---------------------------------------------------------------------------
__global__ __launch_bounds__(256) void wconv_kernel(
    const float* __restrict__ Wq, const float* __restrict__ Wk,
    const float* __restrict__ Wv, ushort* __restrict__ Wb)
{
    const int row = blockIdx.x;
    const float* src = row < 64 ? Wq + (size_t)row * C_
                     : row < 128 ? Wk + (size_t)(row - 64) * C_
                     : Wv + (size_t)(row - 128) * C_;
    const int t2 = threadIdx.x * 2;
    float2 v = *(const float2*)&src[t2];
    ushort2 o; o.x = f2bf(v.x); o.y = f2bf(v.y);
    *(ushort2*)&Wb[(size_t)row * C_ + t2] = o;
}

// ---------------------------------------------------------------------------
// Pass B: fused QKV (x read ONCE, transposed+converted in-LDS, MFMA GEMM).
// grid (N/32 = 128 n-tiles, B), block 512 (8 waves). (unchanged this round)
// ---------------------------------------------------------------------------
__global__ __launch_bounds__(512, 2) void qkv_fused(
    const float* __restrict__ x, const ushort* __restrict__ Wb,
    const float* __restrict__ bq, const float* __restrict__ bk,
    const float* __restrict__ bv,
    ushort* __restrict__ qT, ushort* __restrict__ kT, ushort* __restrict__ vB)
{
    __shared__ ushort Xs[32 * 544];

    const int tid = threadIdx.x, w = tid >> 6, lane = tid & 63;
    const int li = lane & 15, qd = lane >> 4;
    const int n0 = blockIdx.x * 32, b = blockIdx.y;

    // ---- stage x[c][n0..n0+31] -> Xs[n][c] bf16 ----
    {
        const int cg = tid >> 3;       // 0..63
        const int ch = tid & 7;        // n-chunk of 4
        #pragma unroll
        for (int r = 0; r < 8; ++r) {
            const int c = r * 64 + cg;
            float4 v = *(const float4*)&x[((size_t)b * C_ + c) * N_ + n0 + ch * 4];
            Xs[(ch * 4 + 0) * 544 + c] = f2bf(v.x);
            Xs[(ch * 4 + 1) * 544 + c] = f2bf(v.y);
            Xs[(ch * 4 + 2) * 544 + c] = f2bf(v.z);
            Xs[(ch * 4 + 3) * 544 + c] = f2bf(v.w);
        }
    }
    __syncthreads();

    const int rb0 = w * 80;
    f4v acc[5][2];
    #pragma unroll
    for (int ot = 0; ot < 5; ++ot)
        #pragma unroll
        for (int nt = 0; nt < 2; ++nt)
            acc[ot][nt] = (f4v){0.f, 0.f, 0.f, 0.f};

    #pragma unroll 2
    for (int kc = 0; kc < C_; kc += 32) {
        s8v aw[5], bx[2];
        #pragma unroll
        for (int ot = 0; ot < 5; ++ot)
            aw[ot] = *(const s8v*)&Wb[(size_t)(rb0 + ot * 16 + li) * C_ + kc + qd * 8];
        #pragma unroll
        for (int nt = 0; nt < 2; ++nt)
            bx[nt] = *(const s8v*)&Xs[(nt * 16 + li) * 544 + kc + qd * 8];
        #pragma unroll
        for (int ot = 0; ot < 5; ++ot) {
            if (rb0 + ot * 16 >= 128) {       // v: swapped -> D[m=n][col=o]
                #pragma unroll
                for (int nt = 0; nt < 2; ++nt)
                    acc[ot][nt] = MF32(bx[nt], aw[ot], acc[ot][nt]);
            } else {                           // q/k: D[m=o][col=n]
                #pragma unroll
                for (int nt = 0; nt < 2; ++nt)
                    acc[ot][nt] = MF32(aw[ot], bx[nt], acc[ot][nt]);
            }
        }
    }

    #pragma unroll
    for (int ot = 0; ot < 5; ++ot) {
        const int rb = rb0 + ot * 16;
        if (rb < 128) {   // q or k: lane col = n, rows = o (qd*4+r)
            ushort* dst = rb < 64 ? qT : kT;
            const float* bias = rb < 64 ? bq : bk;
            const int ob = (rb < 64 ? rb : rb - 64) + qd * 4;
            const float sc = rb < 64 ? LOG2E : 1.0f;
            #pragma unroll
            for (int nt = 0; nt < 2; ++nt) {
                const int n = n0 + nt * 16 + li;
                ushort4 o;
                o.x = f2bf((acc[ot][nt][0] + bias[ob + 0]) * sc);
                o.y = f2bf((acc[ot][nt][1] + bias[ob + 1]) * sc);
                o.z = f2bf((acc[ot][nt][2] + bias[ob + 2]) * sc);
                o.w = f2bf((acc[ot][nt][3] + bias[ob + 3]) * sc);
                *(ushort4*)&dst[((size_t)b * N_ + n) * 64 + ob] = o;
            }
        } else {          // v: lane col = o (c), rows = n
            const int c = rb - 128 + li;
            const float bb = bv[c];
            #pragma unroll
            for (int nt = 0; nt < 2; ++nt) {
                const int n = n0 + nt * 16 + qd * 4;
                ushort4 o;
                o.x = f2bf(acc[ot][nt][0] + bb);
                o.y = f2bf(acc[ot][nt][1] + bb);
                o.z = f2bf(acc[ot][nt][2] + bb);
                o.w = f2bf(acc[ot][nt][3] + bb);
                *(ushort4*)&vB[((size_t)b * C_ + c) * N_ + n] = o;
            }
        }
    }
}

// ---------------------------------------------------------------------------
// Pass C: MFMA flash attention.
// KEY CHANGE (R3): i-tile 64->128, C split across 2 blocks (c-halves).
// Grid (32 i-tiles, 2 c-halves, B) = 256 blocks (1/CU), block 512 (8 waves).
// Per-CU V traffic halves (V read amplification = N/i_tile); S/exp2 computed
// redundantly per c-half (MFMA/VALU pipes are <15% busy - cheap). This
// targets the measured VMEM-throughput pin (R1: 2x VMEM/CU -> exactly 2x dur).
// Wave w: S^T j-slice w*16 over i=128 (sac it=0..7) AND PV c-slice
// c_base + w*32 (ct=0..1). j-tile 128/iter; P ping-pong [128i][136j] bf16.
// LDS 73728 B dynamic (gfx950 allows 160KB/WG). exp2 (log2e folded into q).
// ---------------------------------------------------------------------------
__device__ __forceinline__ void pv_chunk(
    const ushort* __restrict__ Pr, int li, int qd, int cidx,
    const s8v* vf, f4v (&acc)[2][8])
{
    #pragma unroll
    for (int h = 0; h < 2; ++h) {          // halves keep pf live-range at 4
        s8v pf[4];
        #pragma unroll
        for (int g = 0; g < 4; ++g)
            pf[g] = *(const s8v*)&Pr[(size_t)((h * 4 + g) * 16 + li) * 136 + cidx * 32 + qd * 8];
        #pragma unroll
        for (int ct = 0; ct < 2; ++ct)
            #pragma unroll
            for (int g = 0; g < 4; ++g)
                acc[ct][h * 4 + g] = MF32(vf[ct], pf[g], acc[ct][h * 4 + g]);
    }
}

__device__ __forceinline__ void s_phase(
    s8v ck0, s8v ck1, const s8v (&qf)[8][2], float (&lp)[8],
    ushort* __restrict__ Pw, int li, int qd, int w)
{
    #pragma unroll
    for (int h = 0; h < 2; ++h) {          // halves keep sac live-range at 4
        f4v sac[4];
        #pragma unroll
        for (int g = 0; g < 4; ++g) {
            const int it = h * 4 + g;
            sac[g] = (f4v){0.f, 0.f, 0.f, 0.f};
            sac[g] = MF32(ck0, qf[it][0], sac[g]);
            sac[g] = MF32(ck1, qf[it][1], sac[g]);
        }
        #pragma unroll
        for (int g = 0; g < 4; ++g) {
            const int it = h * 4 + g;
            const float p0 = EXP2(sac[g][0]);
            const float p1 = EXP2(sac[g][1]);
            const float p2 = EXP2(sac[g][2]);
            const float p3 = EXP2(sac[g][3]);
            lp[it] += (p0 + p1) + (p2 + p3);
            uint2 u; u.x = pack2bf(p0, p1); u.y = pack2bf(p2, p3);
            *(uint2*)&Pw[(size_t)(it * 16 + li) * 136 + w * 16 + qd * 4] = u;
        }
    }
}

__global__ __launch_bounds__(512, 2) void attn_mfma(
    const ushort* __restrict__ qT, const ushort* __restrict__ kT,
    const ushort* __restrict__ vB, const float* __restrict__ x,
    const float* __restrict__ gamma, float* __restrict__ out)
{
    extern __shared__ char smem[];
    ushort* Pb0 = (ushort*)smem;               // [128][136]
    ushort* Pb1 = (ushort*)(smem + 34816);     // [128][136]
    float*  l_s = (float*)(smem + 69632);      // [8][128]

    const int tid = threadIdx.x, w = tid >> 6, lane = tid & 63;
    const int li = lane & 15, qd = lane >> 4;
    const int i_base = blockIdx.x * 128;
    const int c_base = blockIdx.y * 256;
    const int b = blockIdx.z;

    const ushort* qTb = qT + (size_t)b * N_ * 64;
    const ushort* kTb = kT + (size_t)b * N_ * 64;
    const ushort* vBb = vB + (size_t)b * C_ * N_;

    // persistent Q fragments (B-operand: n=i at li, k=c at qd*8)
    s8v qf[8][2];
    #pragma unroll
    for (int it = 0; it < 8; ++it)
        #pragma unroll
        for (int ks = 0; ks < 2; ++ks)
            qf[it][ks] = *(const s8v*)&qTb[(size_t)(i_base + it * 16 + li) * 64 + ks * 32 + qd * 8];

    f4v acc[2][8];   // [ct][it]: c = c_base+w*32+ct*16+qd*4+r, i = i_base+it*16+li
    #pragma unroll
    for (int ct = 0; ct < 2; ++ct)
        #pragma unroll
        for (int it = 0; it < 8; ++it)
            acc[ct][it] = (f4v){0.f, 0.f, 0.f, 0.f};
    float lp[8] = {0.f, 0.f, 0.f, 0.f, 0.f, 0.f, 0.f, 0.f};

    const ushort* kptr = kTb + (size_t)(w * 16 + li) * 64 + qd * 8;
    const ushort* vptr[2];
    #pragma unroll
    for (int ct = 0; ct < 2; ++ct)
        vptr[ct] = vBb + (size_t)(c_base + w * 32 + ct * 16 + li) * N_ + qd * 8;

    // ---- prologue (interval 0): K(0), V(0)ch0/1, S(0)->Pb0, K(1) ----
    s8v kc0 = *(const s8v*)(kptr);
    s8v kc1 = *(const s8v*)(kptr + 32);
    s8v vcur[4];                                // [ch*2 + ct], ch=0,1
    #pragma unroll
    for (int ch = 0; ch < 2; ++ch)
        #pragma unroll
        for (int ct = 0; ct < 2; ++ct)
            vcur[ch * 2 + ct] = *(const s8v*)(vptr[ct] + ch * 32);

    // K(1) prefetch: in flight across the raw barrier, consumed at S(1)
    s8v kn0 = *(const s8v*)(kptr + (size_t)128 * 64);
    s8v kn1 = *(const s8v*)(kptr + (size_t)128 * 64 + 32);

    s_phase(kc0, kc1, qf, lp, Pb0, li, qd, w);
    BARRIER_LDS();

    // ---- steady: interval t does PV(t-1) + S(t); one raw barrier ----
    #pragma unroll 1
    for (int t = 1; t < N_ / 128; ++t) {
        const ushort* Pr = ((t - 1) & 1) ? Pb1 : Pb0;
        ushort*       Pw = ((t - 1) & 1) ? Pb0 : Pb1;
        const size_t jprev = (size_t)(t - 1) * 128;
        const size_t jcur  = (size_t)t * 128;
        const size_t jnext = (t + 1 < N_ / 128) ? jcur + 128 : 0;

        // K(t) arrives from last interval's prefetch; issue K(t+1)
        s8v ck0 = kn0, ck1 = kn1;
        kn0 = *(const s8v*)(kptr + jnext * 64);
        kn1 = *(const s8v*)(kptr + jnext * 64 + 32);

        // PV(t-1) with rolling V prefetch
        s8v vlt0[2], vlt1[2], vnx[4];
        #pragma unroll
        for (int ct = 0; ct < 2; ++ct)                       // V(t-1) ch2
            vlt0[ct] = *(const s8v*)(vptr[ct] + jprev + 2 * 32);
        pv_chunk(Pr, li, qd, 0, &vcur[0], acc);
        #pragma unroll
        for (int ct = 0; ct < 2; ++ct)                       // V(t-1) ch3
            vlt1[ct] = *(const s8v*)(vptr[ct] + jprev + 3 * 32);
        pv_chunk(Pr, li, qd, 1, &vcur[2], acc);
        #pragma unroll
        for (int ct = 0; ct < 2; ++ct)                       // V(t) ch0 (next interval)
            vnx[ct] = *(const s8v*)(vptr[ct] + jcur);
        pv_chunk(Pr, li, qd, 2, vlt0, acc);
        #pragma unroll
        for (int ct = 0; ct < 2; ++ct)                       // V(t) ch1 (next interval)
            vnx[2 + ct] = *(const s8v*)(vptr[ct] + jcur + 32);
        pv_chunk(Pr, li, qd, 3, vlt1, acc);

        // S(t) -> Pw
        s_phase(ck0, ck1, qf, lp, Pw, li, qd, w);

        #pragma unroll
        for (int k = 0; k < 4; ++k) vcur[k] = vnx[k];
        BARRIER_LDS();
    }

    // ---- final PV(T-1) ----
    {
        const ushort* Pr = ((N_ / 128 - 1) & 1) ? Pb1 : Pb0;
        const size_t jprev = (size_t)(N_ / 128 - 1) * 128;
        s8v vlt0[2], vlt1[2];
        #pragma unroll
        for (int ct = 0; ct < 2; ++ct)
            vlt0[ct] = *(const s8v*)(vptr[ct] + jprev + 2 * 32);
        pv_chunk(Pr, li, qd, 0, &vcur[0], acc);
        #pragma unroll
        for (int ct = 0; ct < 2; ++ct)
            vlt1[ct] = *(const s8v*)(vptr[ct] + jprev + 3 * 32);
        pv_chunk(Pr, li, qd, 1, &vcur[2], acc);
        pv_chunk(Pr, li, qd, 2, vlt0, acc);
        pv_chunk(Pr, li, qd, 3, vlt1, acc);
    }

    // ---- l reduction: qd via shfl, waves (j-slices) via LDS ----
    #pragma unroll
    for (int it = 0; it < 8; ++it) {
        lp[it] += __shfl_xor(lp[it], 16, 64);
        lp[it] += __shfl_xor(lp[it], 32, 64);
    }
    if (qd == 0) {
        #pragma unroll
        for (int it = 0; it < 8; ++it) l_s[w * 128 + it * 16 + li] = lp[it];
    }
    __syncthreads();
    float inv[8];
    #pragma unroll
    for (int it = 0; it < 8; ++it) {
        float t = 0.f;
        #pragma unroll
        for (int ww = 0; ww < 8; ++ww) t += l_s[ww * 128 + it * 16 + li];
        inv[it] = 1.0f / t;
    }

    // ---- epilogue: out = gamma * acc / l + x (each (c,i) owned by one block) ----
    const float g = gamma[0];
    #pragma unroll
    for (int ct = 0; ct < 2; ++ct)
        #pragma unroll
        for (int it = 0; it < 8; ++it) {
            const int i = i_base + it * 16 + li;
            #pragma unroll
            for (int r = 0; r < 4; ++r) {
                const int c = c_base + w * 32 + ct * 16 + qd * 4 + r;
                const size_t off = ((size_t)b * C_ + c) * N_ + i;
                out[off] = g * acc[ct][it][r] * inv[it] + x[off];
            }
        }
}

// ---------------------------------------------------------------------------
extern "C" void kernel_launch(void* const* d_in, const int* in_sizes, int n_in,
                              void* d_out, int out_size, void* d_ws, size_t ws_size,
                              hipStream_t stream)
{
    const float* x     = (const float*)d_in[0];
    const float* Wq    = (const float*)d_in[1];
    const float* bq    = (const float*)d_in[2];
    const float* Wk    = (const float*)d_in[3];
    const float* bk    = (const float*)d_in[4];
    const float* Wv    = (const float*)d_in[5];
    const float* bv    = (const float*)d_in[6];
    const float* gamma = (const float*)d_in[7];
    float* out = (float*)d_out;

    // ws (ushort): vB [B][512][N] | qT [B][N][64] | kT [B][N][64] | Wb [640][512]
    ushort* vB = (ushort*)d_ws;
    ushort* qT = vB + (size_t)B_ * C_ * N_;
    ushort* kT = qT + (size_t)B_ * N_ * 64;
    ushort* Wb = kT + (size_t)B_ * N_ * 64;

    wconv_kernel<<<dim3(640), 256, 0, stream>>>(Wq, Wk, Wv, Wb);
    qkv_fused<<<dim3(N_ / 32, B_), 512, 0, stream>>>(x, Wb, bq, bk, bv, qT, kT, vB);
    attn_mfma<<<dim3(N_ / 128, 2, B_), 512, 73728, stream>>>(qT, kT, vB, x, gamma, out);
}

// Round 4
// 223.235 us; speedup vs baseline: 1.7731x; 1.0523x over previous
//
#include <hip/hip_runtime.h>
#include <math.h>

#define B_ 4
#define C_ 512
#define N_ 4096
#define LOG2E 1.44269504088896f

typedef __attribute__((ext_vector_type(8))) short s8v;   // 8 bf16
typedef __attribute__((ext_vector_type(4))) float f4v;   // MFMA acc

#define MF32(a, b, c) __builtin_amdgcn_mfma_f32_16x16x32_bf16(a, b, c, 0, 0, 0)

#if defined(__has_builtin) && __has_builtin(__builtin_amdgcn_exp2f)
#define EXP2(x) __builtin_amdgcn_exp2f(x)
#else
#define EXP2(x) exp2f(x)
#endif

// Raw barrier: drains LDS ops only (cross-wave P visibility); global-load
// prefetches stay IN FLIGHT across the barrier.
#define BARRIER_LDS() do {                                   \
    __builtin_amdgcn_sched_barrier(0);                       \
    asm volatile("s_waitcnt lgkmcnt(0)" ::: "memory");       \
    __builtin_amdgcn_s_barrier();                            \
    __builtin_amdgcn_sched_barrier(0);                       \
} while (0)

static __device__ __forceinline__ ushort f2bf(float f) {   // RNE
    unsigned u = __float_as_uint(f);
    u += 0x7FFFu + ((u >> 16) & 1u);
    return (ushort)(u >> 16);
}
static __device__ __forceinline__ unsigned pack2bf(float a, float b) {
    unsigned ua = __float_as_uint(a); ua += 0x7FFFu + ((ua >> 16) & 1u);
    unsigned ub = __float_as_uint(b); ub += 0x7FFFu + ((ub >> 16) & 1u);
    return (ua >> 16) | (ub & 0xffff0000u);
}

// ---------------------------------------------------------------------------
// Pass A: Wq|Wk|Wv -> Wb [640][512] bf16
// ---------------------------------------------------------------------------
__global__ __launch_bounds__(256) void wconv_kernel(
    const float* __restrict__ Wq, const float* __restrict__ Wk,
    const float* __restrict__ Wv, ushort* __restrict__ Wb)
{
    const int row = blockIdx.x;
    const float* src = row < 64 ? Wq + (size_t)row * C_
                     : row < 128 ? Wk + (size_t)(row - 64) * C_
                     : Wv + (size_t)(row - 128) * C_;
    const int t2 = threadIdx.x * 2;
    float2 v = *(const float2*)&src[t2];
    ushort2 o; o.x = f2bf(v.x); o.y = f2bf(v.y);
    *(ushort2*)&Wb[(size_t)row * C_ + t2] = o;
}

// ---------------------------------------------------------------------------
// Pass B (REWRITTEN R4): fused QKV.
// KEY CHANGES: n-tile 32->64, grid (N/64, B) = 256 blocks = 1/CU (halves
// per-CU Wb load instrs: each aw fragment now feeds 4 n-tiles); Wb register
// prefetch one k-iter ahead (rolling awc/awn hides the per-iter L2 latency
// that was fully exposed before); Xs [64n][512c] with XOR swizzle
// (idx ^ (n&7)<<3 on short index) -> conflict-free b128 reads, no padding,
// 64 KB dynamic LDS.
// Wave w: o-rows w*80..+79 (5 tiles of 16) x 64 n. Rows <64 q (x log2e),
// <128 k (stored transposed [b][n][64]); rows >=128: v with SWAPPED MFMA
// operands (D[m=n][col=o]) -> ushort4 stores along n into vB [b][c][n].
// ---------------------------------------------------------------------------
__global__ __launch_bounds__(512, 2) void qkv_fused(
    const float* __restrict__ x, const ushort* __restrict__ Wb,
    const float* __restrict__ bq, const float* __restrict__ bk,
    const float* __restrict__ bv,
    ushort* __restrict__ qT, ushort* __restrict__ kT, ushort* __restrict__ vB)
{
    extern __shared__ ushort Xs[];   // [64][512] bf16, XOR-swizzled, 64 KB

    const int tid = threadIdx.x, w = tid >> 6, lane = tid & 63;
    const int li = lane & 15, qd = lane >> 4;
    const int n0 = blockIdx.x * 64, b = blockIdx.y;

    // ---- stage x[c][n0..n0+63] -> Xs[n][c] bf16 (swizzled) ----
    // flat chunk id f = c*16 + nch (nch = 16B chunk of n); lanes consecutive
    // -> 256 B contiguous per c-row, 4 rows per wave-instr.
    #pragma unroll
    for (int r = 0; r < 16; ++r) {
        const int f = r * 512 + tid;
        const int c = f >> 4;          // 0..511
        const int nch = f & 15;        // 4-float chunk in n
        float4 v = *(const float4*)&x[((size_t)b * C_ + c) * N_ + n0 + nch * 4];
        const int n = nch * 4;
        Xs[((n + 0) * 512 + c) ^ (((n + 0) & 7) << 3)] = f2bf(v.x);
        Xs[((n + 1) * 512 + c) ^ (((n + 1) & 7) << 3)] = f2bf(v.y);
        Xs[((n + 2) * 512 + c) ^ (((n + 2) & 7) << 3)] = f2bf(v.z);
        Xs[((n + 3) * 512 + c) ^ (((n + 3) & 7) << 3)] = f2bf(v.w);
    }
    __syncthreads();

    const int rb0 = w * 80;
    const ushort* wrow[5];
    #pragma unroll
    for (int ot = 0; ot < 5; ++ot)
        wrow[ot] = Wb + (size_t)(rb0 + ot * 16 + li) * C_ + qd * 8;

    f4v acc[5][4];
    #pragma unroll
    for (int ot = 0; ot < 5; ++ot)
        #pragma unroll
        for (int nt = 0; nt < 4; ++nt)
            acc[ot][nt] = (f4v){0.f, 0.f, 0.f, 0.f};

    // Wb rolling register prefetch (distance 1 k-iter)
    s8v awc[5], awn[5];
    #pragma unroll
    for (int ot = 0; ot < 5; ++ot)
        awc[ot] = *(const s8v*)(wrow[ot]);

    #pragma unroll 1
    for (int kc = 0; kc < C_; kc += 32) {
        const int kn = (kc + 32 < C_) ? kc + 32 : 0;   // last prefetch harmless
        #pragma unroll
        for (int ot = 0; ot < 5; ++ot)
            awn[ot] = *(const s8v*)(wrow[ot] + kn);

        s8v bx[4];
        #pragma unroll
        for (int nt = 0; nt < 4; ++nt) {
            const int n = nt * 16 + li;                // n&7 == li&7
            bx[nt] = *(const s8v*)&Xs[((n * 512) + kc + qd * 8) ^ ((li & 7) << 3)];
        }

        #pragma unroll
        for (int ot = 0; ot < 5; ++ot) {
            if (rb0 + ot * 16 >= 128) {       // v: swapped -> D[m=n][col=o]
                #pragma unroll
                for (int nt = 0; nt < 4; ++nt)
                    acc[ot][nt] = MF32(bx[nt], awc[ot], acc[ot][nt]);
            } else {                           // q/k: D[m=o][col=n]
                #pragma unroll
                for (int nt = 0; nt < 4; ++nt)
                    acc[ot][nt] = MF32(awc[ot], bx[nt], acc[ot][nt]);
            }
        }
        #pragma unroll
        for (int ot = 0; ot < 5; ++ot) awc[ot] = awn[ot];
    }

    #pragma unroll
    for (int ot = 0; ot < 5; ++ot) {
        const int rb = rb0 + ot * 16;
        if (rb < 128) {   // q or k: lane col = n, rows = o (qd*4+r)
            ushort* dst = rb < 64 ? qT : kT;
            const float* bias = rb < 64 ? bq : bk;
            const int ob = (rb < 64 ? rb : rb - 64) + qd * 4;
            const float sc = rb < 64 ? LOG2E : 1.0f;
            #pragma unroll
            for (int nt = 0; nt < 4; ++nt) {
                const int n = n0 + nt * 16 + li;
                ushort4 o;
                o.x = f2bf((acc[ot][nt][0] + bias[ob + 0]) * sc);
                o.y = f2bf((acc[ot][nt][1] + bias[ob + 1]) * sc);
                o.z = f2bf((acc[ot][nt][2] + bias[ob + 2]) * sc);
                o.w = f2bf((acc[ot][nt][3] + bias[ob + 3]) * sc);
                *(ushort4*)&dst[((size_t)b * N_ + n) * 64 + ob] = o;
            }
        } else {          // v: lane col = o (c), rows = n
            const int c = rb - 128 + li;
            const float bb = bv[c];
            #pragma unroll
            for (int nt = 0; nt < 4; ++nt) {
                const int n = n0 + nt * 16 + qd * 4;
                ushort4 o;
                o.x = f2bf(acc[ot][nt][0] + bb);
                o.y = f2bf(acc[ot][nt][1] + bb);
                o.z = f2bf(acc[ot][nt][2] + bb);
                o.w = f2bf(acc[ot][nt][3] + bb);
                *(ushort4*)&vB[((size_t)b * C_ + c) * N_ + n] = o;
            }
        }
    }
}

// ---------------------------------------------------------------------------
// Pass C: MFMA flash attention (unchanged from R3: 124.6 us measured).
// Grid (32 i-tiles of 128, 2 c-halves, B) = 256 blocks (1/CU), block 512.
// ---------------------------------------------------------------------------
__device__ __forceinline__ void pv_chunk(
    const ushort* __restrict__ Pr, int li, int qd, int cidx,
    const s8v* vf, f4v (&acc)[2][8])
{
    #pragma unroll
    for (int h = 0; h < 2; ++h) {          // halves keep pf live-range at 4
        s8v pf[4];
        #pragma unroll
        for (int g = 0; g < 4; ++g)
            pf[g] = *(const s8v*)&Pr[(size_t)((h * 4 + g) * 16 + li) * 136 + cidx * 32 + qd * 8];
        #pragma unroll
        for (int ct = 0; ct < 2; ++ct)
            #pragma unroll
            for (int g = 0; g < 4; ++g)
                acc[ct][h * 4 + g] = MF32(vf[ct], pf[g], acc[ct][h * 4 + g]);
    }
}

__device__ __forceinline__ void s_phase(
    s8v ck0, s8v ck1, const s8v (&qf)[8][2], float (&lp)[8],
    ushort* __restrict__ Pw, int li, int qd, int w)
{
    #pragma unroll
    for (int h = 0; h < 2; ++h) {          // halves keep sac live-range at 4
        f4v sac[4];
        #pragma unroll
        for (int g = 0; g < 4; ++g) {
            const int it = h * 4 + g;
            sac[g] = (f4v){0.f, 0.f, 0.f, 0.f};
            sac[g] = MF32(ck0, qf[it][0], sac[g]);
            sac[g] = MF32(ck1, qf[it][1], sac[g]);
        }
        #pragma unroll
        for (int g = 0; g < 4; ++g) {
            const int it = h * 4 + g;
            const float p0 = EXP2(sac[g][0]);
            const float p1 = EXP2(sac[g][1]);
            const float p2 = EXP2(sac[g][2]);
            const float p3 = EXP2(sac[g][3]);
            lp[it] += (p0 + p1) + (p2 + p3);
            uint2 u; u.x = pack2bf(p0, p1); u.y = pack2bf(p2, p3);
            *(uint2*)&Pw[(size_t)(it * 16 + li) * 136 + w * 16 + qd * 4] = u;
        }
    }
}

__global__ __launch_bounds__(512, 2) void attn_mfma(
    const ushort* __restrict__ qT, const ushort* __restrict__ kT,
    const ushort* __restrict__ vB, const float* __restrict__ x,
    const float* __restrict__ gamma, float* __restrict__ out)
{
    extern __shared__ char smem[];
    ushort* Pb0 = (ushort*)smem;               // [128][136]
    ushort* Pb1 = (ushort*)(smem + 34816);     // [128][136]
    float*  l_s = (float*)(smem + 69632);      // [8][128]

    const int tid = threadIdx.x, w = tid >> 6, lane = tid & 63;
    const int li = lane & 15, qd = lane >> 4;
    const int i_base = blockIdx.x * 128;
    const int c_base = blockIdx.y * 256;
    const int b = blockIdx.z;

    const ushort* qTb = qT + (size_t)b * N_ * 64;
    const ushort* kTb = kT + (size_t)b * N_ * 64;
    const ushort* vBb = vB + (size_t)b * C_ * N_;

    // persistent Q fragments (B-operand: n=i at li, k=c at qd*8)
    s8v qf[8][2];
    #pragma unroll
    for (int it = 0; it < 8; ++it)
        #pragma unroll
        for (int ks = 0; ks < 2; ++ks)
            qf[it][ks] = *(const s8v*)&qTb[(size_t)(i_base + it * 16 + li) * 64 + ks * 32 + qd * 8];

    f4v acc[2][8];   // [ct][it]: c = c_base+w*32+ct*16+qd*4+r, i = i_base+it*16+li
    #pragma unroll
    for (int ct = 0; ct < 2; ++ct)
        #pragma unroll
        for (int it = 0; it < 8; ++it)
            acc[ct][it] = (f4v){0.f, 0.f, 0.f, 0.f};
    float lp[8] = {0.f, 0.f, 0.f, 0.f, 0.f, 0.f, 0.f, 0.f};

    const ushort* kptr = kTb + (size_t)(w * 16 + li) * 64 + qd * 8;
    const ushort* vptr[2];
    #pragma unroll
    for (int ct = 0; ct < 2; ++ct)
        vptr[ct] = vBb + (size_t)(c_base + w * 32 + ct * 16 + li) * N_ + qd * 8;

    // ---- prologue (interval 0): K(0), V(0)ch0/1, S(0)->Pb0, K(1) ----
    s8v kc0 = *(const s8v*)(kptr);
    s8v kc1 = *(const s8v*)(kptr + 32);
    s8v vcur[4];                                // [ch*2 + ct], ch=0,1
    #pragma unroll
    for (int ch = 0; ch < 2; ++ch)
        #pragma unroll
        for (int ct = 0; ct < 2; ++ct)
            vcur[ch * 2 + ct] = *(const s8v*)(vptr[ct] + ch * 32);

    // K(1) prefetch: in flight across the raw barrier, consumed at S(1)
    s8v kn0 = *(const s8v*)(kptr + (size_t)128 * 64);
    s8v kn1 = *(const s8v*)(kptr + (size_t)128 * 64 + 32);

    s_phase(kc0, kc1, qf, lp, Pb0, li, qd, w);
    BARRIER_LDS();

    // ---- steady: interval t does PV(t-1) + S(t); one raw barrier ----
    #pragma unroll 1
    for (int t = 1; t < N_ / 128; ++t) {
        const ushort* Pr = ((t - 1) & 1) ? Pb1 : Pb0;
        ushort*       Pw = ((t - 1) & 1) ? Pb0 : Pb1;
        const size_t jprev = (size_t)(t - 1) * 128;
        const size_t jcur  = (size_t)t * 128;
        const size_t jnext = (t + 1 < N_ / 128) ? jcur + 128 : 0;

        // K(t) arrives from last interval's prefetch; issue K(t+1)
        s8v ck0 = kn0, ck1 = kn1;
        kn0 = *(const s8v*)(kptr + jnext * 64);
        kn1 = *(const s8v*)(kptr + jnext * 64 + 32);

        // PV(t-1) with rolling V prefetch
        s8v vlt0[2], vlt1[2], vnx[4];
        #pragma unroll
        for (int ct = 0; ct < 2; ++ct)                       // V(t-1) ch2
            vlt0[ct] = *(const s8v*)(vptr[ct] + jprev + 2 * 32);
        pv_chunk(Pr, li, qd, 0, &vcur[0], acc);
        #pragma unroll
        for (int ct = 0; ct < 2; ++ct)                       // V(t-1) ch3
            vlt1[ct] = *(const s8v*)(vptr[ct] + jprev + 3 * 32);
        pv_chunk(Pr, li, qd, 1, &vcur[2], acc);
        #pragma unroll
        for (int ct = 0; ct < 2; ++ct)                       // V(t) ch0 (next interval)
            vnx[ct] = *(const s8v*)(vptr[ct] + jcur);
        pv_chunk(Pr, li, qd, 2, vlt0, acc);
        #pragma unroll
        for (int ct = 0; ct < 2; ++ct)                       // V(t) ch1 (next interval)
            vnx[2 + ct] = *(const s8v*)(vptr[ct] + jcur + 32);
        pv_chunk(Pr, li, qd, 3, vlt1, acc);

        // S(t) -> Pw
        s_phase(ck0, ck1, qf, lp, Pw, li, qd, w);

        #pragma unroll
        for (int k = 0; k < 4; ++k) vcur[k] = vnx[k];
        BARRIER_LDS();
    }

    // ---- final PV(T-1) ----
    {
        const ushort* Pr = ((N_ / 128 - 1) & 1) ? Pb1 : Pb0;
        const size_t jprev = (size_t)(N_ / 128 - 1) * 128;
        s8v vlt0[2], vlt1[2];
        #pragma unroll
        for (int ct = 0; ct < 2; ++ct)
            vlt0[ct] = *(const s8v*)(vptr[ct] + jprev + 2 * 32);
        pv_chunk(Pr, li, qd, 0, &vcur[0], acc);
        #pragma unroll
        for (int ct = 0; ct < 2; ++ct)
            vlt1[ct] = *(const s8v*)(vptr[ct] + jprev + 3 * 32);
        pv_chunk(Pr, li, qd, 1, &vcur[2], acc);
        pv_chunk(Pr, li, qd, 2, vlt0, acc);
        pv_chunk(Pr, li, qd, 3, vlt1, acc);
    }

    // ---- l reduction: qd via shfl, waves (j-slices) via LDS ----
    #pragma unroll
    for (int it = 0; it < 8; ++it) {
        lp[it] += __shfl_xor(lp[it], 16, 64);
        lp[it] += __shfl_xor(lp[it], 32, 64);
    }
    if (qd == 0) {
        #pragma unroll
        for (int it = 0; it < 8; ++it) l_s[w * 128 + it * 16 + li] = lp[it];
    }
    __syncthreads();
    float inv[8];
    #pragma unroll
    for (int it = 0; it < 8; ++it) {
        float t = 0.f;
        #pragma unroll
        for (int ww = 0; ww < 8; ++ww) t += l_s[ww * 128 + it * 16 + li];
        inv[it] = 1.0f / t;
    }

    // ---- epilogue: out = gamma * acc / l + x (each (c,i) owned by one block) ----
    const float g = gamma[0];
    #pragma unroll
    for (int ct = 0; ct < 2; ++ct)
        #pragma unroll
        for (int it = 0; it < 8; ++it) {
            const int i = i_base + it * 16 + li;
            #pragma unroll
            for (int r = 0; r < 4; ++r) {
                const int c = c_base + w * 32 + ct * 16 + qd * 4 + r;
                const size_t off = ((size_t)b * C_ + c) * N_ + i;
                out[off] = g * acc[ct][it][r] * inv[it] + x[off];
            }
        }
}

// ---------------------------------------------------------------------------
extern "C" void kernel_launch(void* const* d_in, const int* in_sizes, int n_in,
                              void* d_out, int out_size, void* d_ws, size_t ws_size,
                              hipStream_t stream)
{
    const float* x     = (const float*)d_in[0];
    const float* Wq    = (const float*)d_in[1];
    const float* bq    = (const float*)d_in[2];
    const float* Wk    = (const float*)d_in[3];
    const float* bk    = (const float*)d_in[4];
    const float* Wv    = (const float*)d_in[5];
    const float* bv    = (const float*)d_in[6];
    const float* gamma = (const float*)d_in[7];
    float* out = (float*)d_out;

    // ws (ushort): vB [B][512][N] | qT [B][N][64] | kT [B][N][64] | Wb [640][512]
    ushort* vB = (ushort*)d_ws;
    ushort* qT = vB + (size_t)B_ * C_ * N_;
    ushort* kT = qT + (size_t)B_ * N_ * 64;
    ushort* Wb = kT + (size_t)B_ * N_ * 64;

    wconv_kernel<<<dim3(640), 256, 0, stream>>>(Wq, Wk, Wv, Wb);
    qkv_fused<<<dim3(N_ / 64, B_), 512, 65536, stream>>>(x, Wb, bq, bk, bv, qT, kT, vB);
    attn_mfma<<<dim3(N_ / 128, 2, B_), 512, 73728, stream>>>(qT, kT, vB, x, gamma, out);
}

// Round 5
// 221.552 us; speedup vs baseline: 1.7865x; 1.0076x over previous
//
#include <hip/hip_runtime.h>
#include <math.h>

#define B_ 4
#define C_ 512
#define N_ 4096
#define LOG2E 1.44269504088896f

typedef __attribute__((ext_vector_type(8))) short s8v;   // 8 bf16
typedef __attribute__((ext_vector_type(4))) float f4v;   // MFMA acc

#define MF32(a, b, c) __builtin_amdgcn_mfma_f32_16x16x32_bf16(a, b, c, 0, 0, 0)

#if defined(__has_builtin) && __has_builtin(__builtin_amdgcn_exp2f)
#define EXP2(x) __builtin_amdgcn_exp2f(x)
#else
#define EXP2(x) exp2f(x)
#endif

// Raw barrier: drains LDS ops only (cross-wave P visibility); global-load
// prefetches stay IN FLIGHT across the barrier.
#define BARRIER_LDS() do {                                   \
    __builtin_amdgcn_sched_barrier(0);                       \
    asm volatile("s_waitcnt lgkmcnt(0)" ::: "memory");       \
    __builtin_amdgcn_s_barrier();                            \
    __builtin_amdgcn_sched_barrier(0);                       \
} while (0)

static __device__ __forceinline__ ushort f2bf(float f) {   // RNE
    unsigned u = __float_as_uint(f);
    u += 0x7FFFu + ((u >> 16) & 1u);
    return (ushort)(u >> 16);
}
static __device__ __forceinline__ unsigned pack2bf(float a, float b) {
    unsigned ua = __float_as_uint(a); ua += 0x7FFFu + ((ua >> 16) & 1u);
    unsigned ub = __float_as_uint(b); ub += 0x7FFFu + ((ub >> 16) & 1u);
    return (ua >> 16) | (ub & 0xffff0000u);
}

// ---------------------------------------------------------------------------
// Pass A: Wq|Wk|Wv -> Wb [640][512] bf16
// ---------------------------------------------------------------------------
__global__ __launch_bounds__(256) void wconv_kernel(
    const float* __restrict__ Wq, const float* __restrict__ Wk,
    const float* __restrict__ Wv, ushort* __restrict__ Wb)
{
    const int row = blockIdx.x;
    const float* src = row < 64 ? Wq + (size_t)row * C_
                     : row < 128 ? Wk + (size_t)(row - 64) * C_
                     : Wv + (size_t)(row - 128) * C_;
    const int t2 = threadIdx.x * 2;
    float2 v = *(const float2*)&src[t2];
    ushort2 o; o.x = f2bf(v.x); o.y = f2bf(v.y);
    *(ushort2*)&Wb[(size_t)row * C_ + t2] = o;
}

// ---------------------------------------------------------------------------
// Pass B: fused QKV (unchanged from R4).
// grid (N/64, B) = 256 blocks (1/CU), block 512 (8 waves). Xs [64][512]
// XOR-swizzled, Wb register prefetch 1 k-iter ahead.
// ---------------------------------------------------------------------------
__global__ __launch_bounds__(512, 2) void qkv_fused(
    const float* __restrict__ x, const ushort* __restrict__ Wb,
    const float* __restrict__ bq, const float* __restrict__ bk,
    const float* __restrict__ bv,
    ushort* __restrict__ qT, ushort* __restrict__ kT, ushort* __restrict__ vB)
{
    extern __shared__ ushort Xs[];   // [64][512] bf16, XOR-swizzled, 64 KB

    const int tid = threadIdx.x, w = tid >> 6, lane = tid & 63;
    const int li = lane & 15, qd = lane >> 4;
    const int n0 = blockIdx.x * 64, b = blockIdx.y;

    // ---- stage x[c][n0..n0+63] -> Xs[n][c] bf16 (swizzled) ----
    #pragma unroll
    for (int r = 0; r < 16; ++r) {
        const int f = r * 512 + tid;
        const int c = f >> 4;          // 0..511
        const int nch = f & 15;        // 4-float chunk in n
        float4 v = *(const float4*)&x[((size_t)b * C_ + c) * N_ + n0 + nch * 4];
        const int n = nch * 4;
        Xs[((n + 0) * 512 + c) ^ (((n + 0) & 7) << 3)] = f2bf(v.x);
        Xs[((n + 1) * 512 + c) ^ (((n + 1) & 7) << 3)] = f2bf(v.y);
        Xs[((n + 2) * 512 + c) ^ (((n + 2) & 7) << 3)] = f2bf(v.z);
        Xs[((n + 3) * 512 + c) ^ (((n + 3) & 7) << 3)] = f2bf(v.w);
    }
    __syncthreads();

    const int rb0 = w * 80;
    const ushort* wrow[5];
    #pragma unroll
    for (int ot = 0; ot < 5; ++ot)
        wrow[ot] = Wb + (size_t)(rb0 + ot * 16 + li) * C_ + qd * 8;

    f4v acc[5][4];
    #pragma unroll
    for (int ot = 0; ot < 5; ++ot)
        #pragma unroll
        for (int nt = 0; nt < 4; ++nt)
            acc[ot][nt] = (f4v){0.f, 0.f, 0.f, 0.f};

    // Wb rolling register prefetch (distance 1 k-iter)
    s8v awc[5], awn[5];
    #pragma unroll
    for (int ot = 0; ot < 5; ++ot)
        awc[ot] = *(const s8v*)(wrow[ot]);

    #pragma unroll 1
    for (int kc = 0; kc < C_; kc += 32) {
        const int kn = (kc + 32 < C_) ? kc + 32 : 0;   // last prefetch harmless
        #pragma unroll
        for (int ot = 0; ot < 5; ++ot)
            awn[ot] = *(const s8v*)(wrow[ot] + kn);

        s8v bx[4];
        #pragma unroll
        for (int nt = 0; nt < 4; ++nt) {
            const int n = nt * 16 + li;                // n&7 == li&7
            bx[nt] = *(const s8v*)&Xs[((n * 512) + kc + qd * 8) ^ ((li & 7) << 3)];
        }

        #pragma unroll
        for (int ot = 0; ot < 5; ++ot) {
            if (rb0 + ot * 16 >= 128) {       // v: swapped -> D[m=n][col=o]
                #pragma unroll
                for (int nt = 0; nt < 4; ++nt)
                    acc[ot][nt] = MF32(bx[nt], awc[ot], acc[ot][nt]);
            } else {                           // q/k: D[m=o][col=n]
                #pragma unroll
                for (int nt = 0; nt < 4; ++nt)
                    acc[ot][nt] = MF32(awc[ot], bx[nt], acc[ot][nt]);
            }
        }
        #pragma unroll
        for (int ot = 0; ot < 5; ++ot) awc[ot] = awn[ot];
    }

    #pragma unroll
    for (int ot = 0; ot < 5; ++ot) {
        const int rb = rb0 + ot * 16;
        if (rb < 128) {   // q or k: lane col = n, rows = o (qd*4+r)
            ushort* dst = rb < 64 ? qT : kT;
            const float* bias = rb < 64 ? bq : bk;
            const int ob = (rb < 64 ? rb : rb - 64) + qd * 4;
            const float sc = rb < 64 ? LOG2E : 1.0f;
            #pragma unroll
            for (int nt = 0; nt < 4; ++nt) {
                const int n = n0 + nt * 16 + li;
                ushort4 o;
                o.x = f2bf((acc[ot][nt][0] + bias[ob + 0]) * sc);
                o.y = f2bf((acc[ot][nt][1] + bias[ob + 1]) * sc);
                o.z = f2bf((acc[ot][nt][2] + bias[ob + 2]) * sc);
                o.w = f2bf((acc[ot][nt][3] + bias[ob + 3]) * sc);
                *(ushort4*)&dst[((size_t)b * N_ + n) * 64 + ob] = o;
            }
        } else {          // v: lane col = o (c), rows = n
            const int c = rb - 128 + li;
            const float bb = bv[c];
            #pragma unroll
            for (int nt = 0; nt < 4; ++nt) {
                const int n = n0 + nt * 16 + qd * 4;
                ushort4 o;
                o.x = f2bf(acc[ot][nt][0] + bb);
                o.y = f2bf(acc[ot][nt][1] + bb);
                o.z = f2bf(acc[ot][nt][2] + bb);
                o.w = f2bf(acc[ot][nt][3] + bb);
                *(ushort4*)&vB[((size_t)b * C_ + c) * N_ + n] = o;
            }
        }
    }
}

// ---------------------------------------------------------------------------
// Pass C: MFMA flash attention.
// KEY CHANGES (R5):
// 1. XCD-grouped 1-D grid: 256 blocks; hardware round-robins wg->XCD, so
//    combo = wg & 7 pins all 32 i-tiles of one (b, c_half) onto ONE XCD.
//    Per-XCD working set (V 2MB + K 0.5MB + Q 0.5MB) is L2-resident; per
//    iter all 32 blocks of an XCD read the SAME 80KB V/K chunk from L2.
//    (Previously the V/K stream was L3/fabric-served at ~5.3 TB/s = pin.)
// 2. P buffers: stride 136 -> 128 shorts with XOR 16B-chunk swizzle
//    (chunk ^ (row&7)); kills the 10.5M LDS bank conflicts. LDS 69632 B.
// ---------------------------------------------------------------------------
__device__ __forceinline__ void pv_chunk(
    const ushort* __restrict__ Pr, int li, int qd, int cidx,
    const s8v* vf, f4v (&acc)[2][8])
{
    const int sw = li & 7;             // == row&7 for all rows this lane reads
    #pragma unroll
    for (int h = 0; h < 2; ++h) {          // halves keep pf live-range at 4
        s8v pf[4];
        #pragma unroll
        for (int g = 0; g < 4; ++g)
            pf[g] = *(const s8v*)&Pr[(size_t)((h * 4 + g) * 16 + li) * 128
                                     + (((cidx * 4 + qd) ^ sw) << 3)];
        #pragma unroll
        for (int ct = 0; ct < 2; ++ct)
            #pragma unroll
            for (int g = 0; g < 4; ++g)
                acc[ct][h * 4 + g] = MF32(vf[ct], pf[g], acc[ct][h * 4 + g]);
    }
}

__device__ __forceinline__ void s_phase(
    s8v ck0, s8v ck1, const s8v (&qf)[8][2], float (&lp)[8],
    ushort* __restrict__ Pw, int li, int qd, int w)
{
    const int chunk = w * 2 + (qd >> 1);   // 16B chunk of logical col
    const int off = (qd & 1) * 4;          // 8B offset within chunk (shorts)
    const int sw = li & 7;                 // == row&7
    #pragma unroll
    for (int h = 0; h < 2; ++h) {          // halves keep sac live-range at 4
        f4v sac[4];
        #pragma unroll
        for (int g = 0; g < 4; ++g) {
            const int it = h * 4 + g;
            sac[g] = (f4v){0.f, 0.f, 0.f, 0.f};
            sac[g] = MF32(ck0, qf[it][0], sac[g]);
            sac[g] = MF32(ck1, qf[it][1], sac[g]);
        }
        #pragma unroll
        for (int g = 0; g < 4; ++g) {
            const int it = h * 4 + g;
            const float p0 = EXP2(sac[g][0]);
            const float p1 = EXP2(sac[g][1]);
            const float p2 = EXP2(sac[g][2]);
            const float p3 = EXP2(sac[g][3]);
            lp[it] += (p0 + p1) + (p2 + p3);
            uint2 u; u.x = pack2bf(p0, p1); u.y = pack2bf(p2, p3);
            *(uint2*)&Pw[(size_t)(it * 16 + li) * 128
                         + ((chunk ^ sw) << 3) + off] = u;
        }
    }
}

__global__ __launch_bounds__(512, 2) void attn_mfma(
    const ushort* __restrict__ qT, const ushort* __restrict__ kT,
    const ushort* __restrict__ vB, const float* __restrict__ x,
    const float* __restrict__ gamma, float* __restrict__ out)
{
    extern __shared__ char smem[];
    ushort* Pb0 = (ushort*)smem;               // [128][128] swizzled
    ushort* Pb1 = (ushort*)(smem + 32768);     // [128][128] swizzled
    float*  l_s = (float*)(smem + 65536);      // [8][128]

    const int tid = threadIdx.x, w = tid >> 6, lane = tid & 63;
    const int li = lane & 15, qd = lane >> 4;
    // XCD grouping: hw wg -> XCD = wg%8 (round-robin); all 32 i-tiles of one
    // (b, c_half) combo land on one XCD -> V/K/Q L2-resident per XCD.
    const int wg = blockIdx.x;
    const int i_base = (wg >> 3) * 128;
    const int combo = wg & 7;
    const int b = combo >> 1;
    const int c_base = (combo & 1) * 256;

    const ushort* qTb = qT + (size_t)b * N_ * 64;
    const ushort* kTb = kT + (size_t)b * N_ * 64;
    const ushort* vBb = vB + (size_t)b * C_ * N_;

    // persistent Q fragments (B-operand: n=i at li, k=c at qd*8)
    s8v qf[8][2];
    #pragma unroll
    for (int it = 0; it < 8; ++it)
        #pragma unroll
        for (int ks = 0; ks < 2; ++ks)
            qf[it][ks] = *(const s8v*)&qTb[(size_t)(i_base + it * 16 + li) * 64 + ks * 32 + qd * 8];

    f4v acc[2][8];   // [ct][it]: c = c_base+w*32+ct*16+qd*4+r, i = i_base+it*16+li
    #pragma unroll
    for (int ct = 0; ct < 2; ++ct)
        #pragma unroll
        for (int it = 0; it < 8; ++it)
            acc[ct][it] = (f4v){0.f, 0.f, 0.f, 0.f};
    float lp[8] = {0.f, 0.f, 0.f, 0.f, 0.f, 0.f, 0.f, 0.f};

    const ushort* kptr = kTb + (size_t)(w * 16 + li) * 64 + qd * 8;
    const ushort* vptr[2];
    #pragma unroll
    for (int ct = 0; ct < 2; ++ct)
        vptr[ct] = vBb + (size_t)(c_base + w * 32 + ct * 16 + li) * N_ + qd * 8;

    // ---- prologue (interval 0): K(0), V(0)ch0/1, S(0)->Pb0, K(1) ----
    s8v kc0 = *(const s8v*)(kptr);
    s8v kc1 = *(const s8v*)(kptr + 32);
    s8v vcur[4];                                // [ch*2 + ct], ch=0,1
    #pragma unroll
    for (int ch = 0; ch < 2; ++ch)
        #pragma unroll
        for (int ct = 0; ct < 2; ++ct)
            vcur[ch * 2 + ct] = *(const s8v*)(vptr[ct] + ch * 32);

    // K(1) prefetch: in flight across the raw barrier, consumed at S(1)
    s8v kn0 = *(const s8v*)(kptr + (size_t)128 * 64);
    s8v kn1 = *(const s8v*)(kptr + (size_t)128 * 64 + 32);

    s_phase(kc0, kc1, qf, lp, Pb0, li, qd, w);
    BARRIER_LDS();

    // ---- steady: interval t does PV(t-1) + S(t); one raw barrier ----
    #pragma unroll 1
    for (int t = 1; t < N_ / 128; ++t) {
        const ushort* Pr = ((t - 1) & 1) ? Pb1 : Pb0;
        ushort*       Pw = ((t - 1) & 1) ? Pb0 : Pb1;
        const size_t jprev = (size_t)(t - 1) * 128;
        const size_t jcur  = (size_t)t * 128;
        const size_t jnext = (t + 1 < N_ / 128) ? jcur + 128 : 0;

        // K(t) arrives from last interval's prefetch; issue K(t+1)
        s8v ck0 = kn0, ck1 = kn1;
        kn0 = *(const s8v*)(kptr + jnext * 64);
        kn1 = *(const s8v*)(kptr + jnext * 64 + 32);

        // PV(t-1) with rolling V prefetch
        s8v vlt0[2], vlt1[2], vnx[4];
        #pragma unroll
        for (int ct = 0; ct < 2; ++ct)                       // V(t-1) ch2
            vlt0[ct] = *(const s8v*)(vptr[ct] + jprev + 2 * 32);
        pv_chunk(Pr, li, qd, 0, &vcur[0], acc);
        #pragma unroll
        for (int ct = 0; ct < 2; ++ct)                       // V(t-1) ch3
            vlt1[ct] = *(const s8v*)(vptr[ct] + jprev + 3 * 32);
        pv_chunk(Pr, li, qd, 1, &vcur[2], acc);
        #pragma unroll
        for (int ct = 0; ct < 2; ++ct)                       // V(t) ch0 (next interval)
            vnx[ct] = *(const s8v*)(vptr[ct] + jcur);
        pv_chunk(Pr, li, qd, 2, vlt0, acc);
        #pragma unroll
        for (int ct = 0; ct < 2; ++ct)                       // V(t) ch1 (next interval)
            vnx[2 + ct] = *(const s8v*)(vptr[ct] + jcur + 32);
        pv_chunk(Pr, li, qd, 3, vlt1, acc);

        // S(t) -> Pw
        s_phase(ck0, ck1, qf, lp, Pw, li, qd, w);

        #pragma unroll
        for (int k = 0; k < 4; ++k) vcur[k] = vnx[k];
        BARRIER_LDS();
    }

    // ---- final PV(T-1) ----
    {
        const ushort* Pr = ((N_ / 128 - 1) & 1) ? Pb1 : Pb0;
        const size_t jprev = (size_t)(N_ / 128 - 1) * 128;
        s8v vlt0[2], vlt1[2];
        #pragma unroll
        for (int ct = 0; ct < 2; ++ct)
            vlt0[ct] = *(const s8v*)(vptr[ct] + jprev + 2 * 32);
        pv_chunk(Pr, li, qd, 0, &vcur[0], acc);
        #pragma unroll
        for (int ct = 0; ct < 2; ++ct)
            vlt1[ct] = *(const s8v*)(vptr[ct] + jprev + 3 * 32);
        pv_chunk(Pr, li, qd, 1, &vcur[2], acc);
        pv_chunk(Pr, li, qd, 2, vlt0, acc);
        pv_chunk(Pr, li, qd, 3, vlt1, acc);
    }

    // ---- l reduction: qd via shfl, waves (j-slices) via LDS ----
    #pragma unroll
    for (int it = 0; it < 8; ++it) {
        lp[it] += __shfl_xor(lp[it], 16, 64);
        lp[it] += __shfl_xor(lp[it], 32, 64);
    }
    if (qd == 0) {
        #pragma unroll
        for (int it = 0; it < 8; ++it) l_s[w * 128 + it * 16 + li] = lp[it];
    }
    __syncthreads();
    float inv[8];
    #pragma unroll
    for (int it = 0; it < 8; ++it) {
        float t = 0.f;
        #pragma unroll
        for (int ww = 0; ww < 8; ++ww) t += l_s[ww * 128 + it * 16 + li];
        inv[it] = 1.0f / t;
    }

    // ---- epilogue: out = gamma * acc / l + x (each (c,i) owned by one block) ----
    const float g = gamma[0];
    #pragma unroll
    for (int ct = 0; ct < 2; ++ct)
        #pragma unroll
        for (int it = 0; it < 8; ++it) {
            const int i = i_base + it * 16 + li;
            #pragma unroll
            for (int r = 0; r < 4; ++r) {
                const int c = c_base + w * 32 + ct * 16 + qd * 4 + r;
                const size_t off = ((size_t)b * C_ + c) * N_ + i;
                out[off] = g * acc[ct][it][r] * inv[it] + x[off];
            }
        }
}

// ---------------------------------------------------------------------------
extern "C" void kernel_launch(void* const* d_in, const int* in_sizes, int n_in,
                              void* d_out, int out_size, void* d_ws, size_t ws_size,
                              hipStream_t stream)
{
    const float* x     = (const float*)d_in[0];
    const float* Wq    = (const float*)d_in[1];
    const float* bq    = (const float*)d_in[2];
    const float* Wk    = (const float*)d_in[3];
    const float* bk    = (const float*)d_in[4];
    const float* Wv    = (const float*)d_in[5];
    const float* bv    = (const float*)d_in[6];
    const float* gamma = (const float*)d_in[7];
    float* out = (float*)d_out;

    // ws (ushort): vB [B][512][N] | qT [B][N][64] | kT [B][N][64] | Wb [640][512]
    ushort* vB = (ushort*)d_ws;
    ushort* qT = vB + (size_t)B_ * C_ * N_;
    ushort* kT = qT + (size_t)B_ * N_ * 64;
    ushort* Wb = kT + (size_t)B_ * N_ * 64;

    wconv_kernel<<<dim3(640), 256, 0, stream>>>(Wq, Wk, Wv, Wb);
    qkv_fused<<<dim3(N_ / 64, B_), 512, 65536, stream>>>(x, Wb, bq, bk, bv, qT, kT, vB);
    attn_mfma<<<dim3((N_ / 128) * 2 * B_), 512, 69632, stream>>>(qT, kT, vB, x, gamma, out);
}

// Round 6
// 211.059 us; speedup vs baseline: 1.8753x; 1.0497x over previous
//
#include <hip/hip_runtime.h>
#include <math.h>

#define B_ 4
#define C_ 512
#define N_ 4096
#define LOG2E 1.44269504088896f

typedef __attribute__((ext_vector_type(8))) short s8v;   // 8 bf16
typedef __attribute__((ext_vector_type(4))) float f4v;   // MFMA acc

#define MF32(a, b, c) __builtin_amdgcn_mfma_f32_16x16x32_bf16(a, b, c, 0, 0, 0)

#if defined(__has_builtin) && __has_builtin(__builtin_amdgcn_exp2f)
#define EXP2(x) __builtin_amdgcn_exp2f(x)
#else
#define EXP2(x) exp2f(x)
#endif

// Raw barrier: drains LDS ops only (cross-wave P visibility); global-load
// prefetches stay IN FLIGHT across the barrier.
#define BARRIER_LDS() do {                                   \
    __builtin_amdgcn_sched_barrier(0);                       \
    asm volatile("s_waitcnt lgkmcnt(0)" ::: "memory");       \
    __builtin_amdgcn_s_barrier();                            \
    __builtin_amdgcn_sched_barrier(0);                       \
} while (0)

static __device__ __forceinline__ ushort f2bf(float f) {   // RNE
    unsigned u = __float_as_uint(f);
    u += 0x7FFFu + ((u >> 16) & 1u);
    return (ushort)(u >> 16);
}
static __device__ __forceinline__ unsigned pack2bf(float a, float b) {
    unsigned ua = __float_as_uint(a); ua += 0x7FFFu + ((ua >> 16) & 1u);
    unsigned ub = __float_as_uint(b); ub += 0x7FFFu + ((ub >> 16) & 1u);
    return (ua >> 16) | (ub & 0xffff0000u);
}

// ---------------------------------------------------------------------------
// Pass A: Wq|Wk|Wv -> Wb [640][512] bf16
// ---------------------------------------------------------------------------
__global__ __launch_bounds__(256) void wconv_kernel(
    const float* __restrict__ Wq, const float* __restrict__ Wk,
    const float* __restrict__ Wv, ushort* __restrict__ Wb)
{
    const int row = blockIdx.x;
    const float* src = row < 64 ? Wq + (size_t)row * C_
                     : row < 128 ? Wk + (size_t)(row - 64) * C_
                     : Wv + (size_t)(row - 128) * C_;
    const int t2 = threadIdx.x * 2;
    float2 v = *(const float2*)&src[t2];
    ushort2 o; o.x = f2bf(v.x); o.y = f2bf(v.y);
    *(ushort2*)&Wb[(size_t)row * C_ + t2] = o;
}

// ---------------------------------------------------------------------------
// Pass B: fused QKV (unchanged from R4).
// grid (N/64, B) = 256 blocks (1/CU), block 512 (8 waves). Xs [64][512]
// XOR-swizzled, Wb register prefetch 1 k-iter ahead.
// ---------------------------------------------------------------------------
__global__ __launch_bounds__(512, 2) void qkv_fused(
    const float* __restrict__ x, const ushort* __restrict__ Wb,
    const float* __restrict__ bq, const float* __restrict__ bk,
    const float* __restrict__ bv,
    ushort* __restrict__ qT, ushort* __restrict__ kT, ushort* __restrict__ vB)
{
    extern __shared__ ushort Xs[];   // [64][512] bf16, XOR-swizzled, 64 KB

    const int tid = threadIdx.x, w = tid >> 6, lane = tid & 63;
    const int li = lane & 15, qd = lane >> 4;
    const int n0 = blockIdx.x * 64, b = blockIdx.y;

    // ---- stage x[c][n0..n0+63] -> Xs[n][c] bf16 (swizzled) ----
    #pragma unroll
    for (int r = 0; r < 16; ++r) {
        const int f = r * 512 + tid;
        const int c = f >> 4;          // 0..511
        const int nch = f & 15;        // 4-float chunk in n
        float4 v = *(const float4*)&x[((size_t)b * C_ + c) * N_ + n0 + nch * 4];
        const int n = nch * 4;
        Xs[((n + 0) * 512 + c) ^ (((n + 0) & 7) << 3)] = f2bf(v.x);
        Xs[((n + 1) * 512 + c) ^ (((n + 1) & 7) << 3)] = f2bf(v.y);
        Xs[((n + 2) * 512 + c) ^ (((n + 2) & 7) << 3)] = f2bf(v.z);
        Xs[((n + 3) * 512 + c) ^ (((n + 3) & 7) << 3)] = f2bf(v.w);
    }
    __syncthreads();

    const int rb0 = w * 80;
    const ushort* wrow[5];
    #pragma unroll
    for (int ot = 0; ot < 5; ++ot)
        wrow[ot] = Wb + (size_t)(rb0 + ot * 16 + li) * C_ + qd * 8;

    f4v acc[5][4];
    #pragma unroll
    for (int ot = 0; ot < 5; ++ot)
        #pragma unroll
        for (int nt = 0; nt < 4; ++nt)
            acc[ot][nt] = (f4v){0.f, 0.f, 0.f, 0.f};

    // Wb rolling register prefetch (distance 1 k-iter)
    s8v awc[5], awn[5];
    #pragma unroll
    for (int ot = 0; ot < 5; ++ot)
        awc[ot] = *(const s8v*)(wrow[ot]);

    #pragma unroll 1
    for (int kc = 0; kc < C_; kc += 32) {
        const int kn = (kc + 32 < C_) ? kc + 32 : 0;   // last prefetch harmless
        #pragma unroll
        for (int ot = 0; ot < 5; ++ot)
            awn[ot] = *(const s8v*)(wrow[ot] + kn);

        s8v bx[4];
        #pragma unroll
        for (int nt = 0; nt < 4; ++nt) {
            const int n = nt * 16 + li;                // n&7 == li&7
            bx[nt] = *(const s8v*)&Xs[((n * 512) + kc + qd * 8) ^ ((li & 7) << 3)];
        }

        #pragma unroll
        for (int ot = 0; ot < 5; ++ot) {
            if (rb0 + ot * 16 >= 128) {       // v: swapped -> D[m=n][col=o]
                #pragma unroll
                for (int nt = 0; nt < 4; ++nt)
                    acc[ot][nt] = MF32(bx[nt], awc[ot], acc[ot][nt]);
            } else {                           // q/k: D[m=o][col=n]
                #pragma unroll
                for (int nt = 0; nt < 4; ++nt)
                    acc[ot][nt] = MF32(awc[ot], bx[nt], acc[ot][nt]);
            }
        }
        #pragma unroll
        for (int ot = 0; ot < 5; ++ot) awc[ot] = awn[ot];
    }

    #pragma unroll
    for (int ot = 0; ot < 5; ++ot) {
        const int rb = rb0 + ot * 16;
        if (rb < 128) {   // q or k: lane col = n, rows = o (qd*4+r)
            ushort* dst = rb < 64 ? qT : kT;
            const float* bias = rb < 64 ? bq : bk;
            const int ob = (rb < 64 ? rb : rb - 64) + qd * 4;
            const float sc = rb < 64 ? LOG2E : 1.0f;
            #pragma unroll
            for (int nt = 0; nt < 4; ++nt) {
                const int n = n0 + nt * 16 + li;
                ushort4 o;
                o.x = f2bf((acc[ot][nt][0] + bias[ob + 0]) * sc);
                o.y = f2bf((acc[ot][nt][1] + bias[ob + 1]) * sc);
                o.z = f2bf((acc[ot][nt][2] + bias[ob + 2]) * sc);
                o.w = f2bf((acc[ot][nt][3] + bias[ob + 3]) * sc);
                *(ushort4*)&dst[((size_t)b * N_ + n) * 64 + ob] = o;
            }
        } else {          // v: lane col = o (c), rows = n
            const int c = rb - 128 + li;
            const float bb = bv[c];
            #pragma unroll
            for (int nt = 0; nt < 4; ++nt) {
                const int n = n0 + nt * 16 + qd * 4;
                ushort4 o;
                o.x = f2bf(acc[ot][nt][0] + bb);
                o.y = f2bf(acc[ot][nt][1] + bb);
                o.z = f2bf(acc[ot][nt][2] + bb);
                o.w = f2bf(acc[ot][nt][3] + bb);
                *(ushort4*)&vB[((size_t)b * C_ + c) * N_ + n] = o;
            }
        }
    }
}

// ---------------------------------------------------------------------------
// Pass C: MFMA flash attention, PRODUCER-CONSUMER wave specialization (R6).
// Grid 256 blocks (1/CU, XCD-pinned via wg&7 as R5), block 1024 = 16 waves.
// Waves 0-7  (S-producers): hold Q frags; per iter compute S(t) = K^T Q for
//   their j-slice, exp2, pack -> Pw; track row-sum l.
// Waves 8-15 (PV-consumers): hold acc; per iter read Pr, stream V, 32 MFMA.
// Each SIMD hosts 2 S + 2 PV waves with disjoint pipe usage -> S's VALU
// (exp2/pack) overlaps PV's MFMA, PV's ds_read stalls overlap S's MFMA.
// Total per-CU work per iter is UNCHANGED vs R5 (80 VMEM, 96 MFMA/SIMD,
// same LDS ops) - pure overlap play + T5 setprio on the PV MFMA cluster.
// Both branches execute 33 barriers (matched counts; wave-uniform branch).
// P ping-pong [128][128] XOR-16B-chunk swizzled; LDS 69632 B.
// ---------------------------------------------------------------------------
__device__ __forceinline__ void pv_chunk(
    const ushort* __restrict__ Pr, int li, int qd, int cidx,
    const s8v* vf, f4v (&acc)[2][8])
{
    const int sw = li & 7;             // == row&7 for all rows this lane reads
    #pragma unroll
    for (int h = 0; h < 2; ++h) {          // halves keep pf live-range at 4
        s8v pf[4];
        #pragma unroll
        for (int g = 0; g < 4; ++g)
            pf[g] = *(const s8v*)&Pr[(size_t)((h * 4 + g) * 16 + li) * 128
                                     + (((cidx * 4 + qd) ^ sw) << 3)];
        #pragma unroll
        for (int ct = 0; ct < 2; ++ct)
            #pragma unroll
            for (int g = 0; g < 4; ++g)
                acc[ct][h * 4 + g] = MF32(vf[ct], pf[g], acc[ct][h * 4 + g]);
    }
}

__device__ __forceinline__ void s_phase(
    s8v ck0, s8v ck1, const s8v (&qf)[8][2], float (&lp)[8],
    ushort* __restrict__ Pw, int li, int qd, int w2)
{
    const int chunk = w2 * 2 + (qd >> 1);  // 16B chunk of logical col
    const int off = (qd & 1) * 4;          // 8B offset within chunk (shorts)
    const int sw = li & 7;                 // == row&7
    #pragma unroll
    for (int h = 0; h < 2; ++h) {          // halves keep sac live-range at 4
        f4v sac[4];
        #pragma unroll
        for (int g = 0; g < 4; ++g) {
            const int it = h * 4 + g;
            sac[g] = (f4v){0.f, 0.f, 0.f, 0.f};
            sac[g] = MF32(ck0, qf[it][0], sac[g]);
            sac[g] = MF32(ck1, qf[it][1], sac[g]);
        }
        #pragma unroll
        for (int g = 0; g < 4; ++g) {
            const int it = h * 4 + g;
            const float p0 = EXP2(sac[g][0]);
            const float p1 = EXP2(sac[g][1]);
            const float p2 = EXP2(sac[g][2]);
            const float p3 = EXP2(sac[g][3]);
            lp[it] += (p0 + p1) + (p2 + p3);
            uint2 u; u.x = pack2bf(p0, p1); u.y = pack2bf(p2, p3);
            *(uint2*)&Pw[(size_t)(it * 16 + li) * 128
                         + ((chunk ^ sw) << 3) + off] = u;
        }
    }
}

__global__ __launch_bounds__(1024) void attn_mfma(
    const ushort* __restrict__ qT, const ushort* __restrict__ kT,
    const ushort* __restrict__ vB, const float* __restrict__ x,
    const float* __restrict__ gamma, float* __restrict__ out)
{
    extern __shared__ char smem[];
    ushort* Pb0 = (ushort*)smem;               // [128][128] swizzled
    ushort* Pb1 = (ushort*)(smem + 32768);     // [128][128] swizzled
    float*  l_s = (float*)(smem + 65536);      // [8][128]

    const int tid = threadIdx.x, w = tid >> 6, lane = tid & 63;
    const int li = lane & 15, qd = lane >> 4;
    const int w2 = w & 7;
    // XCD grouping (R5): wg -> XCD = wg%8; all 32 i-tiles of one (b, c_half)
    // combo land on one XCD -> V/K/Q L2-resident per XCD (verified: FETCH 3.2x down).
    const int wg = blockIdx.x;
    const int i_base = (wg >> 3) * 128;
    const int combo = wg & 7;
    const int b = combo >> 1;
    const int c_base = (combo & 1) * 256;

    const ushort* qTb = qT + (size_t)b * N_ * 64;
    const ushort* kTb = kT + (size_t)b * N_ * 64;
    const ushort* vBb = vB + (size_t)b * C_ * N_;

    if (w < 8) {
        // =============== S-producer waves ===============
        s8v qf[8][2];
        #pragma unroll
        for (int it = 0; it < 8; ++it)
            #pragma unroll
            for (int ks = 0; ks < 2; ++ks)
                qf[it][ks] = *(const s8v*)&qTb[(size_t)(i_base + it * 16 + li) * 64 + ks * 32 + qd * 8];
        float lp[8] = {0.f, 0.f, 0.f, 0.f, 0.f, 0.f, 0.f, 0.f};

        const ushort* kptr = kTb + (size_t)(w2 * 16 + li) * 64 + qd * 8;

        // interval 0: K(0), S(0)->Pb0, prefetch K(1)
        s8v kc0 = *(const s8v*)(kptr);
        s8v kc1 = *(const s8v*)(kptr + 32);
        s8v kn0 = *(const s8v*)(kptr + (size_t)128 * 64);
        s8v kn1 = *(const s8v*)(kptr + (size_t)128 * 64 + 32);
        s_phase(kc0, kc1, qf, lp, Pb0, li, qd, w2);
        BARRIER_LDS();                                   // #1

        #pragma unroll 1
        for (int t = 1; t < N_ / 128; ++t) {
            ushort* Pw = ((t - 1) & 1) ? Pb0 : Pb1;
            const size_t jnext = (t + 1 < N_ / 128) ? (size_t)(t + 1) * 128 : 0;
            s8v ck0 = kn0, ck1 = kn1;
            kn0 = *(const s8v*)(kptr + jnext * 64);
            kn1 = *(const s8v*)(kptr + jnext * 64 + 32);
            s_phase(ck0, ck1, qf, lp, Pw, li, qd, w2);
            BARRIER_LDS();                               // #2..#32
        }

        // l reduction: qd via shfl, then stash per-wave partials
        #pragma unroll
        for (int it = 0; it < 8; ++it) {
            lp[it] += __shfl_xor(lp[it], 16, 64);
            lp[it] += __shfl_xor(lp[it], 32, 64);
        }
        if (qd == 0) {
            #pragma unroll
            for (int it = 0; it < 8; ++it) l_s[w2 * 128 + it * 16 + li] = lp[it];
        }
        BARRIER_LDS();                                   // #33
        // producers done
    } else {
        // =============== PV-consumer waves ===============
        f4v acc[2][8];   // [ct][it]: c = c_base+w2*32+ct*16+qd*4+r, i = i_base+it*16+li
        #pragma unroll
        for (int ct = 0; ct < 2; ++ct)
            #pragma unroll
            for (int it = 0; it < 8; ++it)
                acc[ct][it] = (f4v){0.f, 0.f, 0.f, 0.f};

        const ushort* vptr[2];
        #pragma unroll
        for (int ct = 0; ct < 2; ++ct)
            vptr[ct] = vBb + (size_t)(c_base + w2 * 32 + ct * 16 + li) * N_ + qd * 8;

        // interval 0: prefetch V(0) ch0/1
        s8v vcur[4];                                // [ch*2 + ct], ch=0,1
        #pragma unroll
        for (int ch = 0; ch < 2; ++ch)
            #pragma unroll
            for (int ct = 0; ct < 2; ++ct)
                vcur[ch * 2 + ct] = *(const s8v*)(vptr[ct] + ch * 32);
        BARRIER_LDS();                                   // #1

        #pragma unroll 1
        for (int t = 1; t < N_ / 128; ++t) {
            const ushort* Pr = ((t - 1) & 1) ? Pb1 : Pb0;
            const size_t jprev = (size_t)(t - 1) * 128;
            const size_t jcur  = (size_t)t * 128;

            __builtin_amdgcn_s_setprio(1);               // T5: favor consumer MFMA
            s8v vlt0[2], vlt1[2], vnx[4];
            #pragma unroll
            for (int ct = 0; ct < 2; ++ct)               // V(t-1) ch2
                vlt0[ct] = *(const s8v*)(vptr[ct] + jprev + 2 * 32);
            pv_chunk(Pr, li, qd, 0, &vcur[0], acc);
            #pragma unroll
            for (int ct = 0; ct < 2; ++ct)               // V(t-1) ch3
                vlt1[ct] = *(const s8v*)(vptr[ct] + jprev + 3 * 32);
            pv_chunk(Pr, li, qd, 1, &vcur[2], acc);
            #pragma unroll
            for (int ct = 0; ct < 2; ++ct)               // V(t) ch0 (next interval)
                vnx[ct] = *(const s8v*)(vptr[ct] + jcur);
            pv_chunk(Pr, li, qd, 2, vlt0, acc);
            #pragma unroll
            for (int ct = 0; ct < 2; ++ct)               // V(t) ch1 (next interval)
                vnx[2 + ct] = *(const s8v*)(vptr[ct] + jcur + 32);
            pv_chunk(Pr, li, qd, 3, vlt1, acc);
            __builtin_amdgcn_s_setprio(0);

            #pragma unroll
            for (int k = 0; k < 4; ++k) vcur[k] = vnx[k];
            BARRIER_LDS();                               // #2..#32
        }

        // final PV(T-1)
        {
            const ushort* Pr = ((N_ / 128 - 1) & 1) ? Pb1 : Pb0;
            const size_t jprev = (size_t)(N_ / 128 - 1) * 128;
            s8v vlt0[2], vlt1[2];
            #pragma unroll
            for (int ct = 0; ct < 2; ++ct)
                vlt0[ct] = *(const s8v*)(vptr[ct] + jprev + 2 * 32);
            pv_chunk(Pr, li, qd, 0, &vcur[0], acc);
            #pragma unroll
            for (int ct = 0; ct < 2; ++ct)
                vlt1[ct] = *(const s8v*)(vptr[ct] + jprev + 3 * 32);
            pv_chunk(Pr, li, qd, 1, &vcur[2], acc);
            pv_chunk(Pr, li, qd, 2, vlt0, acc);
            pv_chunk(Pr, li, qd, 3, vlt1, acc);
        }
        BARRIER_LDS();                                   // #33 (l_s ready)

        float inv[8];
        #pragma unroll
        for (int it = 0; it < 8; ++it) {
            float t = 0.f;
            #pragma unroll
            for (int ww = 0; ww < 8; ++ww) t += l_s[ww * 128 + it * 16 + li];
            inv[it] = 1.0f / t;
        }

        // epilogue: out = gamma * acc / l + x
        const float g = gamma[0];
        #pragma unroll
        for (int ct = 0; ct < 2; ++ct)
            #pragma unroll
            for (int it = 0; it < 8; ++it) {
                const int i = i_base + it * 16 + li;
                #pragma unroll
                for (int r = 0; r < 4; ++r) {
                    const int c = c_base + w2 * 32 + ct * 16 + qd * 4 + r;
                    const size_t off = ((size_t)b * C_ + c) * N_ + i;
                    out[off] = g * acc[ct][it][r] * inv[it] + x[off];
                }
            }
    }
}

// ---------------------------------------------------------------------------
extern "C" void kernel_launch(void* const* d_in, const int* in_sizes, int n_in,
                              void* d_out, int out_size, void* d_ws, size_t ws_size,
                              hipStream_t stream)
{
    const float* x     = (const float*)d_in[0];
    const float* Wq    = (const float*)d_in[1];
    const float* bq    = (const float*)d_in[2];
    const float* Wk    = (const float*)d_in[3];
    const float* bk    = (const float*)d_in[4];
    const float* Wv    = (const float*)d_in[5];
    const float* bv    = (const float*)d_in[6];
    const float* gamma = (const float*)d_in[7];
    float* out = (float*)d_out;

    // ws (ushort): vB [B][512][N] | qT [B][N][64] | kT [B][N][64] | Wb [640][512]
    ushort* vB = (ushort*)d_ws;
    ushort* qT = vB + (size_t)B_ * C_ * N_;
    ushort* kT = qT + (size_t)B_ * N_ * 64;
    ushort* Wb = kT + (size_t)B_ * N_ * 64;

    wconv_kernel<<<dim3(640), 256, 0, stream>>>(Wq, Wk, Wv, Wb);
    qkv_fused<<<dim3(N_ / 64, B_), 512, 65536, stream>>>(x, Wb, bq, bk, bv, qT, kT, vB);
    attn_mfma<<<dim3((N_ / 128) * 2 * B_), 1024, 69632, stream>>>(qT, kT, vB, x, gamma, out);
}